// Round 1
// baseline (10307.510 us; speedup 1.0000x reference)
//
#include <hip/hip_runtime.h>

constexpr int D = 300;

static inline int cdiv(int a, int b){ return (a + b - 1) / b; }

__device__ __forceinline__ unsigned encf(float f){
  unsigned u = __float_as_uint(f);
  return (u >> 31) ? ~u : (u | 0x80000000u);
}
__device__ __forceinline__ float decf(unsigned k){
  return (k & 0x80000000u) ? __uint_as_float(k ^ 0x80000000u) : __uint_as_float(~k);
}

// ---------------- init: xf0 = emb_atom[x0] + emb_chir[x1] ----------------
__global__ void k_embed(const int* __restrict__ x, const float* __restrict__ emb_atom,
                        const float* __restrict__ emb_chir, float* __restrict__ out, int N){
  int idx = blockIdx.x * blockDim.x + threadIdx.x;
  if (idx >= N * D) return;
  int n = idx / D, j = idx - n * D;
  out[idx] = emb_atom[x[2*n] * D + j] + emb_chir[x[2*n+1] * D + j];
}

// ---------------- generic C[M][NC] = A[M][K] @ W[NC][K]^T (+bias/act) ----
// MODE 0: none, 1: bias + leaky_relu(0.01), 2: bias + elu
template<int MODE>
__global__ void k_gemm(const float* __restrict__ A, int K,
                       const float* __restrict__ W, int ldw,
                       const float* __restrict__ bias,
                       float* __restrict__ C, int M, int NC){
  __shared__ float As[16][68];   // k-major, 16B-aligned rows (68*4=272B)
  __shared__ float Bs[16][68];
  int tid = threadIdx.x;
  int tx = tid & 15, ty = tid >> 4;
  int rowBase = blockIdx.y * 64;
  int colBase = blockIdx.x * 64;
  float acc[4][4] = {};
  for (int k0 = 0; k0 < K; k0 += 16){
    #pragma unroll
    for (int s = 0; s < 4; ++s){
      int l = tid + s * 256;
      int rr = l >> 4, kk = l & 15;
      int gk = k0 + kk;
      int gr = rowBase + rr;
      As[kk][rr] = (gr < M && gk < K) ? A[(size_t)gr * K + gk] : 0.f;
      int gc = colBase + rr;
      Bs[kk][rr] = (gc < NC && gk < K) ? W[(size_t)gc * ldw + gk] : 0.f;
    }
    __syncthreads();
    #pragma unroll
    for (int k = 0; k < 16; ++k){
      float a[4], b[4];
      #pragma unroll
      for (int i = 0; i < 4; ++i) a[i] = As[k][ty*4 + i];
      #pragma unroll
      for (int j = 0; j < 4; ++j) b[j] = Bs[k][tx*4 + j];
      #pragma unroll
      for (int i = 0; i < 4; ++i)
        #pragma unroll
        for (int j = 0; j < 4; ++j)
          acc[i][j] += a[i] * b[j];
    }
    __syncthreads();
  }
  #pragma unroll
  for (int i = 0; i < 4; ++i){
    int r = rowBase + ty*4 + i;
    if (r >= M) continue;
    #pragma unroll
    for (int j = 0; j < 4; ++j){
      int c = colBase + tx*4 + j;
      if (c >= NC) continue;
      float v = acc[i][j];
      if (MODE) v += bias[c];
      if (MODE == 1) v = v > 0.f ? v : 0.01f * v;
      if (MODE == 2) v = v > 0.f ? v : (expf(v) - 1.f);
      C[(size_t)r * NC + c] = v;
    }
  }
}

// ---------------- T[c] = (ge_e1[t]+ge_e2[d]) @ W1b^T (18 combos) ----------
__global__ void k_table(const float* __restrict__ e1, const float* __restrict__ e2,
                        const float* __restrict__ W1, float* __restrict__ T){
  int c = blockIdx.x, t = c / 3, d = c - 3 * (c / 3);
  __shared__ float se[D];
  for (int k = threadIdx.x; k < D; k += blockDim.x) se[k] = e1[t*D + k] + e2[d*D + k];
  __syncthreads();
  for (int j = threadIdx.x; j < D; j += blockDim.x){
    float s = 0.f;
    for (int k = 0; k < D; ++k) s += se[k] * W1[(size_t)j * 600 + 300 + k];
    T[c*D + j] = s;
  }
}

// ---------------- row dot with vector: out[m] = A[m,:]·v ------------------
__global__ void k_dot(const float* __restrict__ A, const float* __restrict__ v,
                      float* __restrict__ out, int M){
  int w = (blockIdx.x * blockDim.x + threadIdx.x) >> 6;
  int lane = threadIdx.x & 63;
  if (w >= M) return;
  const float* a = A + (size_t)w * D;
  float s = 0.f;
  for (int j = lane; j < D; j += 64) s += a[j] * v[j];
  #pragma unroll
  for (int o = 32; o; o >>= 1) s += __shfl_xor(s, o);
  if (lane == 0) out[w] = s;
}

// ---------------- GATEConv edge passes ------------------------------------
__global__ void k_gate_logit(const float* __restrict__ u, const float* __restrict__ T,
                             const float* __restrict__ att_l, const float* __restrict__ r,
                             const int* __restrict__ ei, const int* __restrict__ ea,
                             float* __restrict__ logit, unsigned* __restrict__ mxenc,
                             int E, int N){
  int w = (blockIdx.x * blockDim.x + threadIdx.x) >> 6;
  int lane = threadIdx.x & 63;
  if (w >= E + N) return;
  int src, dst, c;
  if (w < E){ src = ei[w]; dst = ei[E + w]; c = ea[2*w] * 3 + ea[2*w + 1]; }
  else { src = w - E; dst = src; c = 12; }  // self-loop: bt=4, bd=0
  const float* ur = u + (size_t)src * D;
  const float* Tc = T + c * D;
  float s = 0.f;
  for (int j = lane; j < D; j += 64){
    float xj = ur[j] + Tc[j];
    xj = xj > 0.f ? xj : 0.01f * xj;
    s += xj * att_l[j];
  }
  #pragma unroll
  for (int o = 32; o; o >>= 1) s += __shfl_xor(s, o);
  if (lane == 0){
    float a = s + r[dst];
    a = a > 0.f ? a : 0.01f * a;
    logit[w] = a;
    atomicMax(mxenc + dst, encf(a));
  }
}

__global__ void k_gate_expsum(float* __restrict__ logit, const unsigned* __restrict__ mxenc,
                              float* __restrict__ sum, const int* __restrict__ ei, int E, int N){
  int w = blockIdx.x * blockDim.x + threadIdx.x;
  if (w >= E + N) return;
  int dst = (w < E) ? ei[E + w] : (w - E);
  float e = expf(logit[w] - decf(mxenc[dst]));
  logit[w] = e;
  atomicAdd(sum + dst, e);
}

__global__ void k_gate_scatter(const float* __restrict__ u, const float* __restrict__ T,
                               const int* __restrict__ ei, const int* __restrict__ ea,
                               const float* __restrict__ ebuf, const float* __restrict__ sum,
                               float* __restrict__ S, int E, int N){
  int w = (blockIdx.x * blockDim.x + threadIdx.x) >> 6;
  int lane = threadIdx.x & 63;
  if (w >= E + N) return;
  int src, dst, c;
  if (w < E){ src = ei[w]; dst = ei[E + w]; c = ea[2*w] * 3 + ea[2*w + 1]; }
  else { src = w - E; dst = src; c = 12; }
  float alpha = ebuf[w] / (sum[dst] + 1e-16f);
  const float* ur = u + (size_t)src * D;
  const float* Tc = T + c * D;
  float* srow = S + (size_t)dst * D;
  for (int j = lane; j < D; j += 64){
    float xj = ur[j] + Tc[j];
    xj = xj > 0.f ? xj : 0.01f * xj;
    atomicAdd(srow + j, xj * alpha);
  }
}

// ---------------- GATConv edge passes -------------------------------------
__global__ void k_gat_logit(const float* __restrict__ as_, const float* __restrict__ ad,
                            const int* __restrict__ ei, float* __restrict__ logit,
                            unsigned* __restrict__ mxenc, int E){
  int w = blockIdx.x * blockDim.x + threadIdx.x;
  if (w >= E) return;
  float a = as_[ei[w]] + ad[ei[E + w]];
  a = a > 0.f ? a : 0.2f * a;
  logit[w] = a;
  atomicMax(mxenc + ei[E + w], encf(a));
}

__global__ void k_expsum_idx(float* __restrict__ logit, const unsigned* __restrict__ mxenc,
                             float* __restrict__ sum, const int* __restrict__ idx, int n){
  int w = blockIdx.x * blockDim.x + threadIdx.x;
  if (w >= n) return;
  int d = idx[w];
  float e = expf(logit[w] - decf(mxenc[d]));
  logit[w] = e;
  atomicAdd(sum + d, e);
}

// generic weighted scatter: S[didx[i]] += V[src?src[i]:i] * alpha[i]
__global__ void k_scatter(const float* __restrict__ V, const int* __restrict__ src,
                          const int* __restrict__ didx, const float* __restrict__ ebuf,
                          const float* __restrict__ sum, float* __restrict__ S, int n){
  int w = (blockIdx.x * blockDim.x + threadIdx.x) >> 6;
  int lane = threadIdx.x & 63;
  if (w >= n) return;
  int sr = src ? src[w] : w;
  int d = didx[w];
  float alpha = ebuf[w] / (sum[d] + 1e-16f);
  const float* vr = V + (size_t)sr * D;
  float* srow = S + (size_t)d * D;
  for (int j = lane; j < D; j += 64) atomicAdd(srow + j, vr[j] * alpha);
}

__global__ void k_mol_logit(const float* __restrict__ asx, const float* __restrict__ ad,
                            const int* __restrict__ batch, float* __restrict__ logit,
                            unsigned* __restrict__ mxenc, int N){
  int w = blockIdx.x * blockDim.x + threadIdx.x;
  if (w >= N) return;
  int g = batch[w];
  float a = asx[w] + ad[g];
  a = a > 0.f ? a : 0.2f * a;
  logit[w] = a;
  atomicMax(mxenc + g, encf(a));
}

// ---------------- elementwise helpers -------------------------------------
__global__ void k_bias_elu(float* __restrict__ X, const float* __restrict__ b, int rows){
  int idx = blockIdx.x * blockDim.x + threadIdx.x;
  if (idx >= rows * D) return;
  int j = idx % D;
  float v = X[idx] + b[j];
  X[idx] = v > 0.f ? v : (expf(v) - 1.f);
}

__global__ void k_relu(float* __restrict__ X, int n){
  int idx = blockIdx.x * blockDim.x + threadIdx.x;
  if (idx >= n) return;
  float v = X[idx];
  X[idx] = v > 0.f ? v : 0.f;
}

__global__ void k_gru_gate(const float* __restrict__ gi, const float* __restrict__ gh,
                           const float* __restrict__ bih, const float* __restrict__ bhh,
                           const float* __restrict__ hprev, float* __restrict__ out, int total){
  int idx = blockIdx.x * blockDim.x + threadIdx.x;
  if (idx >= total) return;
  int rr = idx / D, j = idx - rr * D;
  const float* gir = gi + (size_t)rr * 900;
  const float* ghr = gh + (size_t)rr * 900;
  float ir  = gir[j]       + bih[j];
  float iz  = gir[300 + j] + bih[300 + j];
  float in_ = gir[600 + j] + bih[600 + j];
  float hr  = ghr[j]       + bhh[j];
  float hz  = ghr[300 + j] + bhh[300 + j];
  float hn  = ghr[600 + j] + bhh[600 + j];
  float r = 1.f / (1.f + expf(-(ir + hr)));
  float z = 1.f / (1.f + expf(-(iz + hz)));
  float nn = tanhf(in_ + r * hn);
  float h = hprev[idx];
  float o = (1.f - z) * nn + z * h;
  out[idx] = o > 0.f ? o : 0.f;
}

__global__ void k_segsum(const float* __restrict__ xf, const int* __restrict__ batch,
                         float* __restrict__ OUT, int N){
  int w = (blockIdx.x * blockDim.x + threadIdx.x) >> 6;
  int lane = threadIdx.x & 63;
  if (w >= N) return;
  int g = batch[w];
  const float* xr = xf + (size_t)w * D;
  float* orow = OUT + (size_t)g * D;
  for (int j = lane; j < D; j += 64) atomicAdd(orow + j, xr[j]);
}

__global__ void k_final(const float* __restrict__ OUT, const float* __restrict__ w2,
                        const float* __restrict__ b2, float* __restrict__ out, int G){
  int g = (blockIdx.x * blockDim.x + threadIdx.x) >> 6;
  int lane = threadIdx.x & 63;
  if (g >= G) return;
  float s = 0.f;
  for (int j = lane; j < D; j += 64){
    float v = OUT[(size_t)g * D + j];
    out[(size_t)g * D + j] = v;
    s += v * w2[j];
  }
  #pragma unroll
  for (int o = 32; o; o >>= 1) s += __shfl_xor(s, o);
  if (lane == 0) out[(size_t)G * D + g] = s + b2[0];
}

// ===========================================================================
extern "C" void kernel_launch(void* const* d_in, const int* in_sizes, int n_in,
                              void* d_out, int out_size, void* d_ws, size_t ws_size,
                              hipStream_t stream){
  (void)n_in;
  const int*   x         = (const int*)d_in[0];
  const int*   ei        = (const int*)d_in[1];
  const int*   ea        = (const int*)d_in[2];
  const int*   batch     = (const int*)d_in[3];
  const float* emb_atom  = (const float*)d_in[4];
  const float* emb_chir  = (const float*)d_in[5];
  const float* lin1_W    = (const float*)d_in[6];
  const float* lin1_b    = (const float*)d_in[7];
  const float* ge_e1     = (const float*)d_in[8];
  const float* ge_e2     = (const float*)d_in[9];
  const float* ge_att_l  = (const float*)d_in[10];
  const float* ge_att_r  = (const float*)d_in[11];
  const float* ge_lin1_W = (const float*)d_in[12];
  const float* ge_lin2_W = (const float*)d_in[13];
  const float* ge_bias   = (const float*)d_in[14];
  const float* gat_W     = (const float*)d_in[15];
  const float* gat_att_s = (const float*)d_in[16];
  const float* gat_att_d = (const float*)d_in[17];
  const float* gat_b     = (const float*)d_in[18];
  const float* gru_wih   = (const float*)d_in[19];
  const float* gru_whh   = (const float*)d_in[20];
  const float* gru_bih   = (const float*)d_in[21];
  const float* gru_bhh   = (const float*)d_in[22];
  const float* mol_Ws    = (const float*)d_in[23];
  const float* mol_Wd    = (const float*)d_in[24];
  const float* mol_att_s = (const float*)d_in[25];
  const float* mol_att_d = (const float*)d_in[26];
  const float* mol_b     = (const float*)d_in[27];
  const float* mgru_wih  = (const float*)d_in[28];
  const float* mgru_whh  = (const float*)d_in[29];
  const float* mgru_bih  = (const float*)d_in[30];
  const float* mgru_bhh  = (const float*)d_in[31];
  const float* lin2_W    = (const float*)d_in[32];
  const float* lin2_b    = (const float*)d_in[33];

  const int N  = in_sizes[0] / 2;
  const int E  = in_sizes[1] / 2;
  const int G  = out_size / (D + 1);
  const int EN = E + N;

  char* base = (char*)d_ws;
  size_t used = 0;
  auto alloc = [&](size_t bytes) -> void* {
    void* p = base + used;
    used += (bytes + 255) & ~(size_t)255;
    return p;
  };
  float*    bufA  = (float*)alloc((size_t)N * D * 4);
  float*    bufB  = (float*)alloc((size_t)N * D * 4);
  float*    bufC  = (float*)alloc((size_t)N * D * 4);
  float*    Tt    = (float*)alloc(18 * D * 4);
  float*    rv    = (float*)alloc((size_t)N * 4);
  float*    adv   = (float*)alloc((size_t)N * 4);
  float*    asx   = (float*)alloc((size_t)N * 4);
  float*    logit = (float*)alloc((size_t)EN * 4);
  unsigned* mxenc = (unsigned*)alloc((size_t)N * 4);
  float*    sum   = (float*)alloc((size_t)N * 4);
  float*    OUT   = (float*)alloc((size_t)G * D * 4);
  float*    SG    = (float*)alloc((size_t)G * D * 4);
  float*    xdG   = (float*)alloc((size_t)G * D * 4);

  // remaining workspace -> two GRU gate buffers (row-chunked to fit)
  size_t remain = ws_size > used ? ws_size - used : 0;
  size_t half = (remain / 2) & ~(size_t)255;
  size_t maxbig = ((size_t)N * 900 * 4 + 255) & ~(size_t)255;
  if (half > maxbig) half = maxbig;
  float* big1 = (float*)alloc(half);
  float* big2 = (float*)alloc(half);
  int chunk = (int)(half / (900 * 4));
  if (chunk > N) chunk = N;
  if (chunk < 64) chunk = 64;

  auto gemm = [&](const float* A, const float* W, int ldw, const float* bias,
                  float* Cp, int M, int NC, int mode){
    dim3 grid(cdiv(NC, 64), cdiv(M, 64));
    if (mode == 0)      k_gemm<0><<<grid, 256, 0, stream>>>(A, D, W, ldw, bias, Cp, M, NC);
    else if (mode == 1) k_gemm<1><<<grid, 256, 0, stream>>>(A, D, W, ldw, bias, Cp, M, NC);
    else                k_gemm<2><<<grid, 256, 0, stream>>>(A, D, W, ldw, bias, Cp, M, NC);
  };

  auto gru = [&](const float* inp, const float* hprev,
                 const float* wih, const float* whh,
                 const float* bih, const float* bhh,
                 float* outp, int rows_total){
    for (int r0 = 0; r0 < rows_total; r0 += chunk){
      int rows = rows_total - r0; if (rows > chunk) rows = chunk;
      gemm(inp   + (size_t)r0 * D, wih, D, nullptr, big1, rows, 900, 0);
      gemm(hprev + (size_t)r0 * D, whh, D, nullptr, big2, rows, 900, 0);
      int tot = rows * D;
      k_gru_gate<<<cdiv(tot, 256), 256, 0, stream>>>(big1, big2, bih, bhh,
          hprev + (size_t)r0 * D, outp + (size_t)r0 * D, tot);
    }
  };

  // ---- init features ----
  k_embed<<<cdiv(N * D, 256), 256, 0, stream>>>(x, emb_atom, emb_chir, bufB, N);
  gemm(bufB, lin1_W, D, lin1_b, bufA, N, D, 1);           // xf -> bufA

  // ---- GATEConv ----
  k_table<<<18, 256, 0, stream>>>(ge_e1, ge_e2, ge_lin1_W, Tt);
  gemm(bufA, ge_lin1_W, 2 * D, nullptr, bufB, N, D, 0);   // u = xf @ W1a^T -> bufB
  k_dot<<<cdiv(N, 4), 256, 0, stream>>>(bufA, ge_att_r, rv, N);
  hipMemsetAsync(mxenc, 0, (size_t)N * 4, stream);
  hipMemsetAsync(sum,   0, (size_t)N * 4, stream);
  k_gate_logit<<<cdiv(EN, 4), 256, 0, stream>>>(bufB, Tt, ge_att_l, rv, ei, ea, logit, mxenc, E, N);
  k_gate_expsum<<<cdiv(EN, 256), 256, 0, stream>>>(logit, mxenc, sum, ei, E, N);
  hipMemsetAsync(bufC, 0, (size_t)N * D * 4, stream);
  k_gate_scatter<<<cdiv(EN, 4), 256, 0, stream>>>(bufB, Tt, ei, ea, logit, sum, bufC, E, N);
  gemm(bufC, ge_lin2_W, D, ge_bias, bufB, N, D, 2);       // elu(h) -> bufB
  gru(bufB, bufA, gru_wih, gru_whh, gru_bih, gru_bhh, bufC, N);  // xf -> bufC

  float* xf = bufC; float* t1 = bufA; float* t2 = bufB;
  // ---- GATConv layers 1..4 ----
  for (int l = 0; l < 4; ++l){
    gemm(xf, gat_W + (size_t)l * D * D, D, nullptr, t1, N, D, 0);  // xw -> t1
    k_dot<<<cdiv(N, 4), 256, 0, stream>>>(t1, gat_att_s + l * D, rv, N);
    k_dot<<<cdiv(N, 4), 256, 0, stream>>>(t1, gat_att_d + l * D, adv, N);
    hipMemsetAsync(mxenc, 0, (size_t)N * 4, stream);
    hipMemsetAsync(sum,   0, (size_t)N * 4, stream);
    k_gat_logit<<<cdiv(E, 256), 256, 0, stream>>>(rv, adv, ei, logit, mxenc, E);
    k_expsum_idx<<<cdiv(E, 256), 256, 0, stream>>>(logit, mxenc, sum, ei + E, E);
    hipMemsetAsync(t2, 0, (size_t)N * D * 4, stream);
    k_scatter<<<cdiv(E, 4), 256, 0, stream>>>(t1, ei, ei + E, logit, sum, t2, E);
    k_bias_elu<<<cdiv(N * D, 256), 256, 0, stream>>>(t2, gat_b + l * D, N);
    gru(t2, xf, gru_wih + (size_t)(l + 1) * 270000, gru_whh + (size_t)(l + 1) * 270000,
        gru_bih + (l + 1) * 900, gru_bhh + (l + 1) * 900, t1, N);  // xf_new -> t1
    float* tmp = xf; xf = t1; t1 = tmp;
  }

  // ---- attentive readout ----
  hipMemsetAsync(OUT, 0, (size_t)G * D * 4, stream);
  k_segsum<<<cdiv(N, 4), 256, 0, stream>>>(xf, batch, OUT, N);
  k_relu<<<cdiv(G * D, 256), 256, 0, stream>>>(OUT, G * D);
  gemm(xf, mol_Ws, D, nullptr, t1, N, D, 0);              // xs -> t1 (loop-invariant)
  k_dot<<<cdiv(N, 4), 256, 0, stream>>>(t1, mol_att_s, asx, N);
  for (int t = 0; t < 3; ++t){
    gemm(OUT, mol_Wd, D, nullptr, xdG, G, D, 0);
    k_dot<<<cdiv(G, 4), 256, 0, stream>>>(xdG, mol_att_d, adv, G);
    hipMemsetAsync(mxenc, 0, (size_t)G * 4, stream);
    hipMemsetAsync(sum,   0, (size_t)G * 4, stream);
    k_mol_logit<<<cdiv(N, 256), 256, 0, stream>>>(asx, adv, batch, logit, mxenc, N);
    k_expsum_idx<<<cdiv(N, 256), 256, 0, stream>>>(logit, mxenc, sum, batch, N);
    hipMemsetAsync(SG, 0, (size_t)G * D * 4, stream);
    k_scatter<<<cdiv(N, 4), 256, 0, stream>>>(t1, nullptr, batch, logit, sum, SG, N);
    k_bias_elu<<<cdiv(G * D, 256), 256, 0, stream>>>(SG, mol_b, G);
    gru(SG, OUT, mgru_wih, mgru_whh, mgru_bih, mgru_bhh, OUT, G);  // in-place OK (elementwise)
  }
  k_final<<<cdiv(G, 4), 256, 0, stream>>>(OUT, lin2_W, lin2_b, (float*)d_out, G);
}

// Round 3
// 6332.729 us; speedup vs baseline: 1.6277x; 1.6277x over previous
//
#include <hip/hip_runtime.h>

constexpr int D = 300;
constexpr int KP = 320;   // K padded to multiple of 32

static inline int cdiv(int a, int b){ return (a + b - 1) / b; }

__device__ __forceinline__ unsigned encf(float f){
  unsigned u = __float_as_uint(f);
  return (u >> 31) ? ~u : (u | 0x80000000u);
}
__device__ __forceinline__ float decf(unsigned k){
  return (k & 0x80000000u) ? __uint_as_float(k ^ 0x80000000u) : __uint_as_float(~k);
}
__device__ __forceinline__ unsigned short f2bf(float f){
  unsigned u = __float_as_uint(f);
  unsigned r = (u + 0x7fffu + ((u >> 16) & 1u)) >> 16;
  return (unsigned short)r;
}
__device__ __forceinline__ float bf2f(unsigned short h){
  return __uint_as_float((unsigned)h << 16);
}
// read hi/lo plane pair
__device__ __forceinline__ float pread(const unsigned short* __restrict__ h,
                                       const unsigned short* __restrict__ l, size_t i){
  return bf2f(h[i]) + bf2f(l[i]);
}

typedef __attribute__((ext_vector_type(8))) short bf16x8;
typedef __attribute__((ext_vector_type(4))) float f32x4;

// ------- fp32 [M x 300] (row stride ld) -> hi/lo bf16 planes [Mpad x 320] ---
__global__ void k_cvt2(const float* __restrict__ src, int ld, int M,
                       unsigned short* __restrict__ hb, unsigned short* __restrict__ lb,
                       int total /*Mpad*80*/){
  int idx = blockIdx.x * blockDim.x + threadIdx.x;
  if (idx >= total) return;
  int r = idx / 80, k4 = (idx - r * 80) * 4;
  const float* row = src + (size_t)r * ld;
  bool rm = r < M;
  ushort4 oh, ol;
  float x;
  x = (rm && k4 + 0 < D) ? row[k4 + 0] : 0.f; oh.x = f2bf(x); ol.x = f2bf(x - bf2f(oh.x));
  x = (rm && k4 + 1 < D) ? row[k4 + 1] : 0.f; oh.y = f2bf(x); ol.y = f2bf(x - bf2f(oh.y));
  x = (rm && k4 + 2 < D) ? row[k4 + 2] : 0.f; oh.z = f2bf(x); ol.z = f2bf(x - bf2f(oh.z));
  x = (rm && k4 + 3 < D) ? row[k4 + 3] : 0.f; oh.w = f2bf(x); ol.w = f2bf(x - bf2f(oh.w));
  *(ushort4*)(hb + (size_t)r * KP + k4) = oh;
  *(ushort4*)(lb + (size_t)r * KP + k4) = ol;
}

// ------- bf16x3 MFMA gemm: C = A @ B^T with A,B as hi/lo plane pairs -------
// MODE 0: none, 1: bias+leaky(0.01), 2: bias+elu.  OUTP 0: fp32 C, 1: hi/lo planes.
template<int MODE, int OUTP>
__global__ void k_mfma3(const unsigned short* __restrict__ Ah,
                        const unsigned short* __restrict__ Al,
                        const unsigned short* __restrict__ Bh,
                        const unsigned short* __restrict__ Bl,
                        const float* __restrict__ bias,
                        float* __restrict__ C,
                        unsigned short* __restrict__ Ch, unsigned short* __restrict__ Cl,
                        int M, int NC){
  __shared__ short ls[4][4096];   // Ah,Al,Bh,Bl tiles: [kg(4)][row(128)][8]
  const int tid = threadIdx.x;
  const int lane = tid & 63;
  const int wid = tid >> 6, wr = wid >> 1, wc = wid & 1;
  const int rowBase = blockIdx.y * 128, colBase = blockIdx.x * 128;
  const int l15 = lane & 15, l4 = lane >> 4;
  f32x4 acc[4][4] = {};
  const unsigned short* gsrc[4] = {Ah, Al, Bh, Bl};

  for (int k0 = 0; k0 < KP; k0 += 32){
    #pragma unroll
    for (int t = 0; t < 4; ++t){
      int base = (t < 2) ? rowBase : colBase;
      #pragma unroll
      for (int s = 0; s < 2; ++s){
        int lin = s * 256 + tid;
        int kg = lin >> 7, row = lin & 127;
        const unsigned short* g = gsrc[t] + (size_t)(base + row) * KP + k0 + kg * 8;
        short* lb = &ls[t][0] + (size_t)(s * 256 + (tid & ~63)) * 8;  // wave-uniform base
        __builtin_amdgcn_global_load_lds((const __attribute__((address_space(1))) unsigned*)g,
                                         (__attribute__((address_space(3))) unsigned*)lb, 16, 0, 0);
      }
    }
    __syncthreads();
    bf16x8 fbh[4], fbl[4];
    #pragma unroll
    for (int j = 0; j < 4; ++j){
      int bi = l4 * 128 + wc * 64 + j * 16 + l15;
      fbh[j] = *(const bf16x8*)(&ls[2][0] + (size_t)bi * 8);
      fbl[j] = *(const bf16x8*)(&ls[3][0] + (size_t)bi * 8);
    }
    #pragma unroll
    for (int i = 0; i < 4; ++i){
      int ai = l4 * 128 + wr * 64 + i * 16 + l15;
      bf16x8 fah = *(const bf16x8*)(&ls[0][0] + (size_t)ai * 8);
      bf16x8 fal = *(const bf16x8*)(&ls[1][0] + (size_t)ai * 8);
      #pragma unroll
      for (int j = 0; j < 4; ++j){
        acc[i][j] = __builtin_amdgcn_mfma_f32_16x16x32_bf16(fah, fbh[j], acc[i][j], 0, 0, 0);
        acc[i][j] = __builtin_amdgcn_mfma_f32_16x16x32_bf16(fah, fbl[j], acc[i][j], 0, 0, 0);
        acc[i][j] = __builtin_amdgcn_mfma_f32_16x16x32_bf16(fal, fbh[j], acc[i][j], 0, 0, 0);
      }
    }
    __syncthreads();
  }

  #pragma unroll
  for (int i = 0; i < 4; ++i){
    #pragma unroll
    for (int q = 0; q < 4; ++q){
      int r = rowBase + wr * 64 + i * 16 + l4 * 4 + q;
      if (r >= M) continue;
      #pragma unroll
      for (int j = 0; j < 4; ++j){
        int c = colBase + wc * 64 + j * 16 + l15;
        if (OUTP == 0){
          if (c >= NC) continue;
          float v = acc[i][j][q];
          if (MODE) v += bias[c];
          if (MODE == 1) v = v > 0.f ? v : 0.01f * v;
          if (MODE == 2) v = v > 0.f ? v : (expf(v) - 1.f);
          C[(size_t)r * NC + c] = v;
        } else {
          if (c >= KP) continue;
          size_t o = (size_t)r * KP + c;
          if (c >= NC){ Ch[o] = 0; Cl[o] = 0; continue; }   // keep K-pad zero
          float v = acc[i][j][q];
          if (MODE) v += bias[c];
          if (MODE == 1) v = v > 0.f ? v : 0.01f * v;
          if (MODE == 2) v = v > 0.f ? v : (expf(v) - 1.f);
          unsigned short hi = f2bf(v);
          Ch[o] = hi; Cl[o] = f2bf(v - bf2f(hi));
        }
      }
    }
  }
}

// ---------------- init: xf0 = emb_atom[x0] + emb_chir[x1] ----------------
__global__ void k_embed(const int* __restrict__ x, const float* __restrict__ emb_atom,
                        const float* __restrict__ emb_chir, float* __restrict__ out, int N){
  int idx = blockIdx.x * blockDim.x + threadIdx.x;
  if (idx >= N * D) return;
  int n = idx / D, j = idx - n * D;
  out[idx] = emb_atom[x[2*n] * D + j] + emb_chir[x[2*n+1] * D + j];
}

// ---------------- T[c] = (ge_e1[t]+ge_e2[d]) @ W1b^T (18 combos, fp32) ----
__global__ void k_table(const float* __restrict__ e1, const float* __restrict__ e2,
                        const float* __restrict__ W1, float* __restrict__ T){
  int c = blockIdx.x, t = c / 3, d = c - 3 * (c / 3);
  __shared__ float se[D];
  for (int k = threadIdx.x; k < D; k += blockDim.x) se[k] = e1[t*D + k] + e2[d*D + k];
  __syncthreads();
  for (int j = threadIdx.x; j < D; j += blockDim.x){
    float s = 0.f;
    for (int k = 0; k < D; ++k) s += se[k] * W1[(size_t)j * 600 + 300 + k];
    T[c*D + j] = s;
  }
}

// ---------------- row dot (plane pair): out[m] = A[m,:]·v -----------------
__global__ void k_dot2(const unsigned short* __restrict__ Ahp, const unsigned short* __restrict__ Alp,
                       const float* __restrict__ v, float* __restrict__ out, int M){
  int w = (blockIdx.x * blockDim.x + threadIdx.x) >> 6;
  int lane = threadIdx.x & 63;
  if (w >= M) return;
  size_t base = (size_t)w * KP;
  float s = 0.f;
  for (int j = lane; j < D; j += 64) s += pread(Ahp, Alp, base + j) * v[j];
  #pragma unroll
  for (int o = 32; o; o >>= 1) s += __shfl_xor(s, o);
  if (lane == 0) out[w] = s;
}

// ---------------- row dot (fp32, stride D) --------------------------------
__global__ void k_dot(const float* __restrict__ A, const float* __restrict__ v,
                      float* __restrict__ out, int M){
  int w = (blockIdx.x * blockDim.x + threadIdx.x) >> 6;
  int lane = threadIdx.x & 63;
  if (w >= M) return;
  const float* a = A + (size_t)w * D;
  float s = 0.f;
  for (int j = lane; j < D; j += 64) s += a[j] * v[j];
  #pragma unroll
  for (int o = 32; o; o >>= 1) s += __shfl_xor(s, o);
  if (lane == 0) out[w] = s;
}

// ---------------- GATEConv edge passes ------------------------------------
__global__ void k_gate_logit(const unsigned short* __restrict__ uh, const unsigned short* __restrict__ ul,
                             const float* __restrict__ T,
                             const float* __restrict__ att_l, const float* __restrict__ r,
                             const int* __restrict__ ei, const int* __restrict__ ea,
                             float* __restrict__ logit, unsigned* __restrict__ mxenc,
                             int E, int N){
  int w = (blockIdx.x * blockDim.x + threadIdx.x) >> 6;
  int lane = threadIdx.x & 63;
  if (w >= E + N) return;
  int src, dst, c;
  if (w < E){ src = ei[w]; dst = ei[E + w]; c = ea[2*w] * 3 + ea[2*w + 1]; }
  else { src = w - E; dst = src; c = 12; }  // self-loop: bt=4, bd=0
  size_t ub = (size_t)src * KP;
  const float* Tc = T + c * D;
  float s = 0.f;
  for (int j = lane; j < D; j += 64){
    float xj = pread(uh, ul, ub + j) + Tc[j];
    xj = xj > 0.f ? xj : 0.01f * xj;
    s += xj * att_l[j];
  }
  #pragma unroll
  for (int o = 32; o; o >>= 1) s += __shfl_xor(s, o);
  if (lane == 0){
    float a = s + r[dst];
    a = a > 0.f ? a : 0.01f * a;
    logit[w] = a;
    atomicMax(mxenc + dst, encf(a));
  }
}

__global__ void k_gate_expsum(float* __restrict__ logit, const unsigned* __restrict__ mxenc,
                              float* __restrict__ sum, const int* __restrict__ ei, int E, int N){
  int w = blockIdx.x * blockDim.x + threadIdx.x;
  if (w >= E + N) return;
  int dst = (w < E) ? ei[E + w] : (w - E);
  float e = expf(logit[w] - decf(mxenc[dst]));
  logit[w] = e;
  atomicAdd(sum + dst, e);
}

__global__ void k_gate_scatter(const unsigned short* __restrict__ uh, const unsigned short* __restrict__ ul,
                               const float* __restrict__ T,
                               const int* __restrict__ ei, const int* __restrict__ ea,
                               const float* __restrict__ ebuf, const float* __restrict__ sum,
                               float* __restrict__ S, int E, int N){
  int w = (blockIdx.x * blockDim.x + threadIdx.x) >> 6;
  int lane = threadIdx.x & 63;
  if (w >= E + N) return;
  int src, dst, c;
  if (w < E){ src = ei[w]; dst = ei[E + w]; c = ea[2*w] * 3 + ea[2*w + 1]; }
  else { src = w - E; dst = src; c = 12; }
  float alpha = ebuf[w] / (sum[dst] + 1e-16f);
  size_t ub = (size_t)src * KP;
  const float* Tc = T + c * D;
  float* srow = S + (size_t)dst * D;
  for (int j = lane; j < D; j += 64){
    float xj = pread(uh, ul, ub + j) + Tc[j];
    xj = xj > 0.f ? xj : 0.01f * xj;
    atomicAdd(srow + j, xj * alpha);
  }
}

// ---------------- GATConv / mol edge passes -------------------------------
__global__ void k_gat_logit(const float* __restrict__ as_, const float* __restrict__ ad,
                            const int* __restrict__ ei, float* __restrict__ logit,
                            unsigned* __restrict__ mxenc, int E){
  int w = blockIdx.x * blockDim.x + threadIdx.x;
  if (w >= E) return;
  float a = as_[ei[w]] + ad[ei[E + w]];
  a = a > 0.f ? a : 0.2f * a;
  logit[w] = a;
  atomicMax(mxenc + ei[E + w], encf(a));
}

__global__ void k_expsum_idx(float* __restrict__ logit, const unsigned* __restrict__ mxenc,
                             float* __restrict__ sum, const int* __restrict__ idx, int n){
  int w = blockIdx.x * blockDim.x + threadIdx.x;
  if (w >= n) return;
  int d = idx[w];
  float e = expf(logit[w] - decf(mxenc[d]));
  logit[w] = e;
  atomicAdd(sum + d, e);
}

// weighted scatter from plane pair: S[didx[i]] += V[src?src[i]:i] * alpha[i]
__global__ void k_scatter(const unsigned short* __restrict__ Vh, const unsigned short* __restrict__ Vl,
                          const int* __restrict__ src,
                          const int* __restrict__ didx, const float* __restrict__ ebuf,
                          const float* __restrict__ sum, float* __restrict__ S, int n){
  int w = (blockIdx.x * blockDim.x + threadIdx.x) >> 6;
  int lane = threadIdx.x & 63;
  if (w >= n) return;
  int sr = src ? src[w] : w;
  int d = didx[w];
  float alpha = ebuf[w] / (sum[d] + 1e-16f);
  size_t vb = (size_t)sr * KP;
  float* srow = S + (size_t)d * D;
  for (int j = lane; j < D; j += 64) atomicAdd(srow + j, pread(Vh, Vl, vb + j) * alpha);
}

__global__ void k_mol_logit(const float* __restrict__ asx, const float* __restrict__ ad,
                            const int* __restrict__ batch, float* __restrict__ logit,
                            unsigned* __restrict__ mxenc, int N){
  int w = blockIdx.x * blockDim.x + threadIdx.x;
  if (w >= N) return;
  int g = batch[w];
  float a = asx[w] + ad[g];
  a = a > 0.f ? a : 0.2f * a;
  logit[w] = a;
  atomicMax(mxenc + g, encf(a));
}

// ---------------- elementwise helpers -------------------------------------
__global__ void k_bias_elu(float* __restrict__ X, const float* __restrict__ b, int rows){
  int idx = blockIdx.x * blockDim.x + threadIdx.x;
  if (idx >= rows * D) return;
  int j = idx % D;
  float v = X[idx] + b[j];
  X[idx] = v > 0.f ? v : (expf(v) - 1.f);
}

__global__ void k_relu(float* __restrict__ X, int n){
  int idx = blockIdx.x * blockDim.x + threadIdx.x;
  if (idx >= n) return;
  float v = X[idx];
  X[idx] = v > 0.f ? v : 0.f;
}

// GRU gate fuse; h read from plane pair (pre-offset by r0*KP); out pre-offset r0*D
__global__ void k_gru_gate(const float* __restrict__ gi, const float* __restrict__ gh,
                           const float* __restrict__ bih, const float* __restrict__ bhh,
                           const unsigned short* __restrict__ Hh, const unsigned short* __restrict__ Hl,
                           float* __restrict__ out, int total){
  int idx = blockIdx.x * blockDim.x + threadIdx.x;
  if (idx >= total) return;
  int rr = idx / D, j = idx - rr * D;
  const float* gir = gi + (size_t)rr * 900;
  const float* ghr = gh + (size_t)rr * 900;
  float ir  = gir[j]       + bih[j];
  float iz  = gir[300 + j] + bih[300 + j];
  float in_ = gir[600 + j] + bih[600 + j];
  float hr  = ghr[j]       + bhh[j];
  float hz  = ghr[300 + j] + bhh[300 + j];
  float hn  = ghr[600 + j] + bhh[600 + j];
  float r = 1.f / (1.f + expf(-(ir + hr)));
  float z = 1.f / (1.f + expf(-(iz + hz)));
  float nn = tanhf(in_ + r * hn);
  float h = pread(Hh, Hl, (size_t)rr * KP + j);
  float o = (1.f - z) * nn + z * h;
  out[idx] = o > 0.f ? o : 0.f;
}

__global__ void k_segsum(const float* __restrict__ xf, const int* __restrict__ batch,
                         float* __restrict__ OUT, int N){
  int w = (blockIdx.x * blockDim.x + threadIdx.x) >> 6;
  int lane = threadIdx.x & 63;
  if (w >= N) return;
  int g = batch[w];
  const float* xr = xf + (size_t)w * D;
  float* orow = OUT + (size_t)g * D;
  for (int j = lane; j < D; j += 64) atomicAdd(orow + j, xr[j]);
}

__global__ void k_final(const float* __restrict__ OUT, const float* __restrict__ w2,
                        const float* __restrict__ b2, float* __restrict__ out, int G){
  int g = (blockIdx.x * blockDim.x + threadIdx.x) >> 6;
  int lane = threadIdx.x & 63;
  if (g >= G) return;
  float s = 0.f;
  for (int j = lane; j < D; j += 64){
    float v = OUT[(size_t)g * D + j];
    out[(size_t)g * D + j] = v;
    s += v * w2[j];
  }
  #pragma unroll
  for (int o = 32; o; o >>= 1) s += __shfl_xor(s, o);
  if (lane == 0) out[(size_t)G * D + g] = s + b2[0];
}

// ===========================================================================
extern "C" void kernel_launch(void* const* d_in, const int* in_sizes, int n_in,
                              void* d_out, int out_size, void* d_ws, size_t ws_size,
                              hipStream_t stream){
  (void)n_in;
  const int*   x         = (const int*)d_in[0];
  const int*   ei        = (const int*)d_in[1];
  const int*   ea        = (const int*)d_in[2];
  const int*   batch     = (const int*)d_in[3];
  const float* emb_atom  = (const float*)d_in[4];
  const float* emb_chir  = (const float*)d_in[5];
  const float* lin1_W    = (const float*)d_in[6];
  const float* lin1_b    = (const float*)d_in[7];
  const float* ge_e1     = (const float*)d_in[8];
  const float* ge_e2     = (const float*)d_in[9];
  const float* ge_att_l  = (const float*)d_in[10];
  const float* ge_att_r  = (const float*)d_in[11];
  const float* ge_lin1_W = (const float*)d_in[12];
  const float* ge_lin2_W = (const float*)d_in[13];
  const float* ge_bias   = (const float*)d_in[14];
  const float* gat_W     = (const float*)d_in[15];
  const float* gat_att_s = (const float*)d_in[16];
  const float* gat_att_d = (const float*)d_in[17];
  const float* gat_b     = (const float*)d_in[18];
  const float* gru_wih   = (const float*)d_in[19];
  const float* gru_whh   = (const float*)d_in[20];
  const float* gru_bih   = (const float*)d_in[21];
  const float* gru_bhh   = (const float*)d_in[22];
  const float* mol_Ws    = (const float*)d_in[23];
  const float* mol_Wd    = (const float*)d_in[24];
  const float* mol_att_s = (const float*)d_in[25];
  const float* mol_att_d = (const float*)d_in[26];
  const float* mol_b     = (const float*)d_in[27];
  const float* mgru_wih  = (const float*)d_in[28];
  const float* mgru_whh  = (const float*)d_in[29];
  const float* mgru_bih  = (const float*)d_in[30];
  const float* mgru_bhh  = (const float*)d_in[31];
  const float* lin2_W    = (const float*)d_in[32];
  const float* lin2_b    = (const float*)d_in[33];

  const int N  = in_sizes[0] / 2;
  const int E  = in_sizes[1] / 2;
  const int G  = out_size / (D + 1);
  const int EN = E + N;
  const int Npad = cdiv(N, 128) * 128;
  const int Gpad = cdiv(G, 128) * 128;

  char* base = (char*)d_ws;
  size_t used = 0;
  auto alloc = [&](size_t bytes) -> void* {
    void* p = base + used;
    used += (bytes + 255) & ~(size_t)255;
    return p;
  };
  typedef unsigned short us;
  // two N-row plane pairs + one fp32 scratch
  us* PaH = (us*)alloc((size_t)Npad * KP * 2);
  us* PaL = (us*)alloc((size_t)Npad * KP * 2);
  us* PbH = (us*)alloc((size_t)Npad * KP * 2);
  us* PbL = (us*)alloc((size_t)Npad * KP * 2);
  float* F = (float*)alloc((size_t)N * D * 4);
  // G-row plane pairs
  us* GaH = (us*)alloc((size_t)Gpad * KP * 2);
  us* GaL = (us*)alloc((size_t)Gpad * KP * 2);
  us* GbH = (us*)alloc((size_t)Gpad * KP * 2);
  us* GbL = (us*)alloc((size_t)Gpad * KP * 2);
  // weights: 9 small (384 rows) + 12 big (1024 rows), hi/lo each
  auto wsm = [&](void){ return (us*)alloc((size_t)384 * KP * 2); };
  auto wbg = [&](void){ return (us*)alloc((size_t)1024 * KP * 2); };
  us *wlin1H=wsm(), *wlin1L=wsm(), *wgeuH=wsm(), *wgeuL=wsm(), *wge2H=wsm(), *wge2L=wsm();
  us *wgatH[4], *wgatL[4];
  for (int l = 0; l < 4; ++l){ wgatH[l]=wsm(); wgatL[l]=wsm(); }
  us *wmolSH=wsm(), *wmolSL=wsm(), *wmolDH=wsm(), *wmolDL=wsm();
  us *wihH[5], *wihL[5], *whhH[5], *whhL[5];
  for (int l = 0; l < 5; ++l){ wihH[l]=wbg(); wihL[l]=wbg(); whhH[l]=wbg(); whhL[l]=wbg(); }
  us *wmgiH=wbg(), *wmgiL=wbg(), *wmghH=wbg(), *wmghL=wbg();
  float*    Tt    = (float*)alloc(18 * D * 4);
  float*    rv    = (float*)alloc((size_t)N * 4);
  float*    adv   = (float*)alloc((size_t)N * 4);
  float*    asx   = (float*)alloc((size_t)N * 4);
  float*    logit = (float*)alloc((size_t)EN * 4);
  unsigned* mxenc = (unsigned*)alloc((size_t)N * 4);
  float*    sum   = (float*)alloc((size_t)N * 4);
  float*    OUT   = (float*)alloc((size_t)G * D * 4);
  float*    SG    = (float*)alloc((size_t)G * D * 4);
  float*    xdG   = (float*)alloc((size_t)G * D * 4);

  // remaining workspace -> two GRU gate buffers (rows multiple of 128)
  size_t remain = ws_size > used ? ws_size - used : 0;
  size_t half = (remain / 2) & ~(size_t)255;
  size_t maxbig = ((size_t)Npad * 900 * 4 + 255) & ~(size_t)255;
  if (half > maxbig) half = maxbig;
  float* big1 = (float*)alloc(half);
  float* big2 = (float*)alloc(half);
  int chunk = (int)(half / (900 * 4)) & ~127;
  if (chunk > Npad) chunk = Npad;
  if (chunk < 128) chunk = 128;

  auto cvt2 = [&](const float* src, int ld, int M, us* hb, us* lb, int Mpad){
    int tot = Mpad * 80;
    k_cvt2<<<cdiv(tot, 256), 256, 0, stream>>>(src, ld, M, hb, lb, tot);
  };
  // gemm -> fp32 C
  auto mm_f = [&](const us* ah, const us* al, const us* bh, const us* bl,
                  const float* bias, float* Cp, int M, int NC, int mode){
    dim3 grid(cdiv(NC, 128), cdiv(M, 128));
    if (mode == 2) k_mfma3<2,0><<<grid, 256, 0, stream>>>(ah, al, bh, bl, bias, Cp, nullptr, nullptr, M, NC);
    else           k_mfma3<0,0><<<grid, 256, 0, stream>>>(ah, al, bh, bl, bias, Cp, nullptr, nullptr, M, NC);
  };
  // gemm -> hi/lo planes
  auto mm_p = [&](const us* ah, const us* al, const us* bh, const us* bl,
                  const float* bias, us* ch, us* cl, int M, int NC, int mode){
    dim3 grid(cdiv(NC, 128), cdiv(M, 128));
    if (mode == 1) k_mfma3<1,1><<<grid, 256, 0, stream>>>(ah, al, bh, bl, bias, nullptr, ch, cl, M, NC);
    else           k_mfma3<0,1><<<grid, 256, 0, stream>>>(ah, al, bh, bl, bias, nullptr, ch, cl, M, NC);
  };

  // ---- convert all weights to hi/lo planes ----
  cvt2(lin1_W, D, D, wlin1H, wlin1L, 384);
  cvt2(ge_lin1_W, 2 * D, D, wgeuH, wgeuL, 384);      // W1a = ge_lin1_W[:, :300]
  cvt2(ge_lin2_W, D, D, wge2H, wge2L, 384);
  for (int l = 0; l < 4; ++l) cvt2(gat_W + (size_t)l * D * D, D, D, wgatH[l], wgatL[l], 384);
  cvt2(mol_Ws, D, D, wmolSH, wmolSL, 384);
  cvt2(mol_Wd, D, D, wmolDH, wmolDL, 384);
  for (int l = 0; l < 5; ++l){
    cvt2(gru_wih + (size_t)l * 270000, D, 900, wihH[l], wihL[l], 1024);
    cvt2(gru_whh + (size_t)l * 270000, D, 900, whhH[l], whhL[l], 1024);
  }
  cvt2(mgru_wih, D, 900, wmgiH, wmgiL, 1024);
  cvt2(mgru_whh, D, 900, wmghH, wmghL, 1024);

  // GRU: input planes (Ih/Il), h planes (Hh/Hl); new state (relu'd) -> fp32 outF
  auto gru = [&](const us* Ih, const us* Il, const us* Hh, const us* Hl,
                 const us* wiH, const us* wiL, const us* whH, const us* whL,
                 const float* bih, const float* bhh, float* outF, int rows_total){
    for (int r0 = 0; r0 < rows_total; r0 += chunk){
      int rows = rows_total - r0; if (rows > chunk) rows = chunk;
      mm_f(Ih + (size_t)r0 * KP, Il + (size_t)r0 * KP, wiH, wiL, nullptr, big1, rows, 900, 0);
      mm_f(Hh + (size_t)r0 * KP, Hl + (size_t)r0 * KP, whH, whL, nullptr, big2, rows, 900, 0);
      int tot = rows * D;
      k_gru_gate<<<cdiv(tot, 256), 256, 0, stream>>>(big1, big2, bih, bhh,
          Hh + (size_t)r0 * KP, Hl + (size_t)r0 * KP, outF + (size_t)r0 * D, tot);
    }
  };

  // ---- init features: emb -> F; planes -> Pa; xf planes -> Pb ----
  k_embed<<<cdiv(N * D, 256), 256, 0, stream>>>(x, emb_atom, emb_chir, F, N);
  cvt2(F, D, N, PaH, PaL, Npad);
  mm_p(PaH, PaL, wlin1H, wlin1L, lin1_b, PbH, PbL, N, D, 1);   // xf planes -> Pb

  // ---- GATEConv ----
  k_table<<<18, 256, 0, stream>>>(ge_e1, ge_e2, ge_lin1_W, Tt);
  mm_p(PbH, PbL, wgeuH, wgeuL, nullptr, PaH, PaL, N, D, 0);    // u planes -> Pa
  k_dot2<<<cdiv(N, 4), 256, 0, stream>>>(PbH, PbL, ge_att_r, rv, N);
  hipMemsetAsync(mxenc, 0, (size_t)N * 4, stream);
  hipMemsetAsync(sum,   0, (size_t)N * 4, stream);
  k_gate_logit<<<cdiv(EN, 4), 256, 0, stream>>>(PaH, PaL, Tt, ge_att_l, rv, ei, ea, logit, mxenc, E, N);
  k_gate_expsum<<<cdiv(EN, 256), 256, 0, stream>>>(logit, mxenc, sum, ei, E, N);
  hipMemsetAsync(F, 0, (size_t)N * D * 4, stream);
  k_gate_scatter<<<cdiv(EN, 4), 256, 0, stream>>>(PaH, PaL, Tt, ei, ea, logit, sum, F, E, N);
  cvt2(F, D, N, PaH, PaL, Npad);                               // S planes -> Pa (u dead)
  mm_f(PaH, PaL, wge2H, wge2L, ge_bias, F, N, D, 2);           // elu(h) fp32 -> F
  cvt2(F, D, N, PaH, PaL, Npad);                               // elu(h) planes -> Pa
  gru(PaH, PaL, PbH, PbL, wihH[0], wihL[0], whhH[0], whhL[0],
      gru_bih, gru_bhh, F, N);                                 // new xf fp32 -> F
  cvt2(F, D, N, PbH, PbL, Npad);                               // xf planes -> Pb

  // ---- GATConv layers 1..4 ----
  for (int l = 0; l < 4; ++l){
    mm_p(PbH, PbL, wgatH[l], wgatL[l], nullptr, PaH, PaL, N, D, 0);  // xw -> Pa
    k_dot2<<<cdiv(N, 4), 256, 0, stream>>>(PaH, PaL, gat_att_s + l * D, rv, N);
    k_dot2<<<cdiv(N, 4), 256, 0, stream>>>(PaH, PaL, gat_att_d + l * D, adv, N);
    hipMemsetAsync(mxenc, 0, (size_t)N * 4, stream);
    hipMemsetAsync(sum,   0, (size_t)N * 4, stream);
    k_gat_logit<<<cdiv(E, 256), 256, 0, stream>>>(rv, adv, ei, logit, mxenc, E);
    k_expsum_idx<<<cdiv(E, 256), 256, 0, stream>>>(logit, mxenc, sum, ei + E, E);
    hipMemsetAsync(F, 0, (size_t)N * D * 4, stream);
    k_scatter<<<cdiv(E, 4), 256, 0, stream>>>(PaH, PaL, ei, ei + E, logit, sum, F, E);
    k_bias_elu<<<cdiv(N * D, 256), 256, 0, stream>>>(F, gat_b + l * D, N);
    cvt2(F, D, N, PaH, PaL, Npad);                             // gate-in planes -> Pa
    gru(PaH, PaL, PbH, PbL, wihH[l+1], wihL[l+1], whhH[l+1], whhL[l+1],
        gru_bih + (l + 1) * 900, gru_bhh + (l + 1) * 900, F, N);
    cvt2(F, D, N, PbH, PbL, Npad);                             // new xf planes -> Pb
  }

  // ---- attentive readout ----
  hipMemsetAsync(OUT, 0, (size_t)G * D * 4, stream);
  k_segsum<<<cdiv(N, 4), 256, 0, stream>>>(F, batch, OUT, N);  // F still holds xf fp32
  k_relu<<<cdiv(G * D, 256), 256, 0, stream>>>(OUT, G * D);
  mm_p(PbH, PbL, wmolSH, wmolSL, nullptr, PaH, PaL, N, D, 0);  // xs planes -> Pa (pinned)
  k_dot2<<<cdiv(N, 4), 256, 0, stream>>>(PaH, PaL, mol_att_s, asx, N);
  for (int t = 0; t < 3; ++t){
    cvt2(OUT, D, G, GaH, GaL, Gpad);                           // OUT planes -> Ga
    mm_f(GaH, GaL, wmolDH, wmolDL, nullptr, xdG, G, D, 0);
    k_dot<<<cdiv(G, 4), 256, 0, stream>>>(xdG, mol_att_d, adv, G);
    hipMemsetAsync(mxenc, 0, (size_t)G * 4, stream);
    hipMemsetAsync(sum,   0, (size_t)G * 4, stream);
    k_mol_logit<<<cdiv(N, 256), 256, 0, stream>>>(asx, adv, batch, logit, mxenc, N);
    k_expsum_idx<<<cdiv(N, 256), 256, 0, stream>>>(logit, mxenc, sum, batch, N);
    hipMemsetAsync(SG, 0, (size_t)G * D * 4, stream);
    k_scatter<<<cdiv(N, 4), 256, 0, stream>>>(PaH, PaL, nullptr, batch, logit, sum, SG, N);
    k_bias_elu<<<cdiv(G * D, 256), 256, 0, stream>>>(SG, mol_b, G);
    cvt2(SG, D, G, GbH, GbL, Gpad);                            // gate-in planes -> Gb
    gru(GbH, GbL, GaH, GaL, wmgiH, wmgiL, wmghH, wmghL,
        mgru_bih, mgru_bhh, OUT, G);                           // new out fp32 -> OUT
  }
  k_final<<<cdiv(G, 4), 256, 0, stream>>>(OUT, lin2_W, lin2_b, (float*)d_out, G);
}

// Round 4
// 4460.504 us; speedup vs baseline: 2.3108x; 1.4197x over previous
//
#include <hip/hip_runtime.h>

constexpr int D = 300;
constexpr int KP = 320;   // K padded to multiple of 32

static inline int cdiv(int a, int b){ return (a + b - 1) / b; }

__device__ __forceinline__ unsigned short f2bf(float f){
  unsigned u = __float_as_uint(f);
  unsigned r = (u + 0x7fffu + ((u >> 16) & 1u)) >> 16;
  return (unsigned short)r;
}
__device__ __forceinline__ float bf2f(unsigned short h){
  return __uint_as_float((unsigned)h << 16);
}
__device__ __forceinline__ float pread(const unsigned short* __restrict__ h,
                                       const unsigned short* __restrict__ l, size_t i){
  return bf2f(h[i]) + bf2f(l[i]);
}
__device__ __forceinline__ void pwrite(unsigned short* __restrict__ h,
                                       unsigned short* __restrict__ l, size_t i, float v){
  unsigned short hi = f2bf(v);
  h[i] = hi; l[i] = f2bf(v - bf2f(hi));
}

typedef __attribute__((ext_vector_type(8))) short bf16x8;
typedef __attribute__((ext_vector_type(4))) float f32x4;
typedef unsigned short us;

// ------- fp32 [M x 300] (row stride ld) -> hi/lo bf16 planes [Mpad x 320] ---
__global__ void k_cvt2(const float* __restrict__ src, int ld, int M,
                       us* __restrict__ hb, us* __restrict__ lb, int total){
  int idx = blockIdx.x * blockDim.x + threadIdx.x;
  if (idx >= total) return;
  int r = idx / 80, k4 = (idx - r * 80) * 4;
  const float* row = src + (size_t)r * ld;
  bool rm = r < M;
  ushort4 oh, ol;
  float x;
  x = (rm && k4 + 0 < D) ? row[k4 + 0] : 0.f; oh.x = f2bf(x); ol.x = f2bf(x - bf2f(oh.x));
  x = (rm && k4 + 1 < D) ? row[k4 + 1] : 0.f; oh.y = f2bf(x); ol.y = f2bf(x - bf2f(oh.y));
  x = (rm && k4 + 2 < D) ? row[k4 + 2] : 0.f; oh.z = f2bf(x); ol.z = f2bf(x - bf2f(oh.z));
  x = (rm && k4 + 3 < D) ? row[k4 + 3] : 0.f; oh.w = f2bf(x); ol.w = f2bf(x - bf2f(oh.w));
  *(ushort4*)(hb + (size_t)r * KP + k4) = oh;
  *(ushort4*)(lb + (size_t)r * KP + k4) = ol;
}

// ------- bf16x3 MFMA gemm: planes = A @ B^T, A/B hi-lo plane pairs ---------
// MODE 0: none, 1: bias+leaky(0.01), 2: bias+elu. Output always planes.
template<int MODE>
__global__ void k_mfma3(const us* __restrict__ Ah, const us* __restrict__ Al,
                        const us* __restrict__ Bh, const us* __restrict__ Bl,
                        const float* __restrict__ bias,
                        us* __restrict__ Ch, us* __restrict__ Cl,
                        int M, int NC){
  __shared__ short ls[4][4096];   // Ah,Al,Bh,Bl tiles: [kg(4)][row(128)][8]
  const int tid = threadIdx.x;
  const int lane = tid & 63;
  const int wid = tid >> 6, wr = wid >> 1, wc = wid & 1;
  const int rowBase = blockIdx.y * 128, colBase = blockIdx.x * 128;
  const int l15 = lane & 15, l4 = lane >> 4;
  f32x4 acc[4][4] = {};
  const us* gsrc[4] = {Ah, Al, Bh, Bl};

  for (int k0 = 0; k0 < KP; k0 += 32){
    #pragma unroll
    for (int t = 0; t < 4; ++t){
      int base = (t < 2) ? rowBase : colBase;
      #pragma unroll
      for (int s = 0; s < 2; ++s){
        int lin = s * 256 + tid;
        int kg = lin >> 7, row = lin & 127;
        const us* g = gsrc[t] + (size_t)(base + row) * KP + k0 + kg * 8;
        short* lb = &ls[t][0] + (size_t)(s * 256 + (tid & ~63)) * 8;
        __builtin_amdgcn_global_load_lds((const __attribute__((address_space(1))) unsigned*)g,
                                         (__attribute__((address_space(3))) unsigned*)lb, 16, 0, 0);
      }
    }
    __syncthreads();
    bf16x8 fbh[4], fbl[4];
    #pragma unroll
    for (int j = 0; j < 4; ++j){
      int bi = l4 * 128 + wc * 64 + j * 16 + l15;
      fbh[j] = *(const bf16x8*)(&ls[2][0] + (size_t)bi * 8);
      fbl[j] = *(const bf16x8*)(&ls[3][0] + (size_t)bi * 8);
    }
    #pragma unroll
    for (int i = 0; i < 4; ++i){
      int ai = l4 * 128 + wr * 64 + i * 16 + l15;
      bf16x8 fah = *(const bf16x8*)(&ls[0][0] + (size_t)ai * 8);
      bf16x8 fal = *(const bf16x8*)(&ls[1][0] + (size_t)ai * 8);
      #pragma unroll
      for (int j = 0; j < 4; ++j){
        acc[i][j] = __builtin_amdgcn_mfma_f32_16x16x32_bf16(fah, fbh[j], acc[i][j], 0, 0, 0);
        acc[i][j] = __builtin_amdgcn_mfma_f32_16x16x32_bf16(fah, fbl[j], acc[i][j], 0, 0, 0);
        acc[i][j] = __builtin_amdgcn_mfma_f32_16x16x32_bf16(fal, fbh[j], acc[i][j], 0, 0, 0);
      }
    }
    __syncthreads();
  }

  #pragma unroll
  for (int i = 0; i < 4; ++i){
    #pragma unroll
    for (int q = 0; q < 4; ++q){
      int r = rowBase + wr * 64 + i * 16 + l4 * 4 + q;
      if (r >= M) continue;
      #pragma unroll
      for (int j = 0; j < 4; ++j){
        int c = colBase + wc * 64 + j * 16 + l15;
        if (c >= KP) continue;
        size_t o = (size_t)r * KP + c;
        if (c >= NC){ Ch[o] = 0; Cl[o] = 0; continue; }
        float v = acc[i][j][q];
        if (MODE) v += bias[c];
        if (MODE == 1) v = v > 0.f ? v : 0.01f * v;
        if (MODE == 2) v = v > 0.f ? v : (expf(v) - 1.f);
        pwrite(Ch, Cl, o, v);
      }
    }
  }
}

// ---------------- fully-fused GRU: out = relu(gru(in, h)) -> planes -------
// block = 128 rows x 16 j's; weights [1024 x KP] planes, rows g*300+j
__global__ __launch_bounds__(256) void k_gru(
    const us* __restrict__ Ih, const us* __restrict__ Il,
    const us* __restrict__ Hh, const us* __restrict__ Hl,
    const us* __restrict__ WiH, const us* __restrict__ WiL,
    const us* __restrict__ WhH, const us* __restrict__ WhL,
    const float* __restrict__ bih, const float* __restrict__ bhh,
    us* __restrict__ Oh, us* __restrict__ Ol){
  __shared__ short lsA[4][4096];   // Ih,Il,Hh,Hl: [kg(4)][row(128)][8]
  __shared__ short lsW[12][512];   // [(m*3+g)*2+pl]: [kg(4)][row(16)][8]
  const int tid = threadIdx.x, lane = tid & 63, wid = tid >> 6;
  const int l15 = lane & 15, l4 = lane >> 4;
  const int j0 = blockIdx.x * 16;
  const int rowBase = blockIdx.y * 128;
  f32x4 acc[2][6] = {};
  const us* asrc[4] = {Ih, Il, Hh, Hl};
  const us* wsrc[4] = {WiH, WiL, WhH, WhL};

  for (int k0 = 0; k0 < KP; k0 += 32){
    #pragma unroll
    for (int t = 0; t < 4; ++t){
      #pragma unroll
      for (int s = 0; s < 2; ++s){
        int lin = s * 256 + tid;
        int kg = lin >> 7, row = lin & 127;
        const us* g = asrc[t] + (size_t)(rowBase + row) * KP + k0 + kg * 8;
        short* dst = &lsA[t][0] + (size_t)(s * 256 + (tid & ~63)) * 8;
        __builtin_amdgcn_global_load_lds((const __attribute__((address_space(1))) unsigned*)g,
                                         (__attribute__((address_space(3))) unsigned*)dst, 16, 0, 0);
      }
    }
    #pragma unroll
    for (int ss = 0; ss < 3; ++ss){
      int ti = wid * 3 + ss;           // 0..11
      int m  = ti / 6;                 // 0: Wih, 1: Whh
      int gg = (ti / 2) % 3;           // gate
      int pl = ti & 1;                 // plane
      const us* g = wsrc[m * 2 + pl] + (size_t)(gg * 300 + j0 + l15) * KP + k0 + l4 * 8;
      short* dst = &lsW[ti][0];
      __builtin_amdgcn_global_load_lds((const __attribute__((address_space(1))) unsigned*)g,
                                       (__attribute__((address_space(3))) unsigned*)dst, 16, 0, 0);
    }
    __syncthreads();
    bf16x8 bw[12];
    #pragma unroll
    for (int ti = 0; ti < 12; ++ti)
      bw[ti] = *(const bf16x8*)(&lsW[ti][0] + (size_t)(l4 * 16 + l15) * 8);
    #pragma unroll
    for (int r = 0; r < 2; ++r){
      int ar = wid * 32 + r * 16 + l15;
      bf16x8 aih = *(const bf16x8*)(&lsA[0][0] + (size_t)(l4 * 128 + ar) * 8);
      bf16x8 ail = *(const bf16x8*)(&lsA[1][0] + (size_t)(l4 * 128 + ar) * 8);
      bf16x8 ahh = *(const bf16x8*)(&lsA[2][0] + (size_t)(l4 * 128 + ar) * 8);
      bf16x8 ahl = *(const bf16x8*)(&lsA[3][0] + (size_t)(l4 * 128 + ar) * 8);
      #pragma unroll
      for (int gg = 0; gg < 3; ++gg){
        bf16x8 bh_i = bw[gg * 2 + 0], bl_i = bw[gg * 2 + 1];
        bf16x8 bh_h = bw[6 + gg * 2 + 0], bl_h = bw[6 + gg * 2 + 1];
        acc[r][gg] = __builtin_amdgcn_mfma_f32_16x16x32_bf16(aih, bh_i, acc[r][gg], 0, 0, 0);
        acc[r][gg] = __builtin_amdgcn_mfma_f32_16x16x32_bf16(aih, bl_i, acc[r][gg], 0, 0, 0);
        acc[r][gg] = __builtin_amdgcn_mfma_f32_16x16x32_bf16(ail, bh_i, acc[r][gg], 0, 0, 0);
        acc[r][3+gg] = __builtin_amdgcn_mfma_f32_16x16x32_bf16(ahh, bh_h, acc[r][3+gg], 0, 0, 0);
        acc[r][3+gg] = __builtin_amdgcn_mfma_f32_16x16x32_bf16(ahh, bl_h, acc[r][3+gg], 0, 0, 0);
        acc[r][3+gg] = __builtin_amdgcn_mfma_f32_16x16x32_bf16(ahl, bh_h, acc[r][3+gg], 0, 0, 0);
      }
    }
    __syncthreads();
  }

  int j = j0 + l15;
  if (j < D){
    float b0 = bih[j], b1 = bih[j+300], b2 = bih[j+600];
    float c0 = bhh[j], c1 = bhh[j+300], c2 = bhh[j+600];
    #pragma unroll
    for (int r = 0; r < 2; ++r){
      #pragma unroll
      for (int q = 0; q < 4; ++q){
        int row = rowBase + wid * 32 + r * 16 + l4 * 4 + q;
        float ir = acc[r][0][q] + b0, iz = acc[r][1][q] + b1, in_ = acc[r][2][q] + b2;
        float hr = acc[r][3][q] + c0, hz = acc[r][4][q] + c1, hn  = acc[r][5][q] + c2;
        float rg = 1.f / (1.f + expf(-(ir + hr)));
        float zg = 1.f / (1.f + expf(-(iz + hz)));
        float nn = tanhf(in_ + rg * hn);
        float h = pread(Hh, Hl, (size_t)row * KP + j);
        float o = (1.f - zg) * nn + zg * h;
        o = o > 0.f ? o : 0.f;
        pwrite(Oh, Ol, (size_t)row * KP + j, o);
      }
    }
  }
}

// ---------------- init: planes of emb_atom[x0]+emb_chir[x1] ----------------
__global__ void k_embed2(const int* __restrict__ x, const float* __restrict__ ea,
                         const float* __restrict__ ec, us* __restrict__ hb,
                         us* __restrict__ lb, int N, int total){
  int idx = blockIdx.x * blockDim.x + threadIdx.x;
  if (idx >= total) return;
  int r = idx / KP, j = idx - r * KP;
  float v = (r < N && j < D) ? ea[x[2*r] * D + j] + ec[x[2*r+1] * D + j] : 0.f;
  pwrite(hb, lb, idx, v);
}

// ---------------- T[c] = (ge_e1[t]+ge_e2[d]) @ W1b^T (18 combos, fp32) ----
__global__ void k_table(const float* __restrict__ e1, const float* __restrict__ e2,
                        const float* __restrict__ W1, float* __restrict__ T){
  int c = blockIdx.x, t = c / 3, d = c - 3 * (c / 3);
  __shared__ float se[D];
  for (int k = threadIdx.x; k < D; k += blockDim.x) se[k] = e1[t*D + k] + e2[d*D + k];
  __syncthreads();
  for (int j = threadIdx.x; j < D; j += blockDim.x){
    float s = 0.f;
    for (int k = 0; k < D; ++k) s += se[k] * W1[(size_t)j * 600 + 300 + k];
    T[c*D + j] = s;
  }
}

// ---------------- row dot (plane pair) ------------------------------------
__global__ void k_dot2(const us* __restrict__ Ahp, const us* __restrict__ Alp,
                       const float* __restrict__ v, float* __restrict__ out, int M){
  int w = (blockIdx.x * blockDim.x + threadIdx.x) >> 6;
  int lane = threadIdx.x & 63;
  if (w >= M) return;
  size_t base = (size_t)w * KP;
  float s = 0.f;
  for (int j = lane; j < D; j += 64) s += pread(Ahp, Alp, base + j) * v[j];
  #pragma unroll
  for (int o = 32; o; o >>= 1) s += __shfl_xor(s, o);
  if (lane == 0) out[w] = s;
}

// ---------------- CSR build ------------------------------------------------
__global__ void k_hist(const int* __restrict__ ei, int E, int* __restrict__ hist){
  int e = blockIdx.x * blockDim.x + threadIdx.x;
  if (e < E) atomicAdd(&hist[ei[E + e]], 1);
}
template<int BS>
__global__ void k_scanA(const int* __restrict__ in, int* __restrict__ out,
                        int* __restrict__ bsum, int n){
  __shared__ int s[BS];
  int t = threadIdx.x, gid = blockIdx.x * BS + t;
  int v = (gid < n) ? in[gid] : 0;
  s[t] = v; __syncthreads();
  for (int o = 1; o < BS; o <<= 1){
    int add = (t >= o) ? s[t - o] : 0;
    __syncthreads();
    s[t] += add;
    __syncthreads();
  }
  if (gid < n) out[gid] = s[t] - v;
  if (t == BS - 1) bsum[blockIdx.x] = s[BS - 1];
}
template<int BS>
__global__ void k_scanB(int* __restrict__ bsum, int nb){
  __shared__ int s[BS];
  int t = threadIdx.x;
  int v = (t < nb) ? bsum[t] : 0;
  s[t] = v; __syncthreads();
  for (int o = 1; o < BS; o <<= 1){
    int add = (t >= o) ? s[t - o] : 0;
    __syncthreads();
    s[t] += add;
    __syncthreads();
  }
  if (t < nb) bsum[t] = s[t] - v;
}
template<int BS>
__global__ void k_scanC(int* __restrict__ out, const int* __restrict__ bsum, int n){
  int gid = blockIdx.x * BS + threadIdx.x;
  if (gid < n) out[gid] += bsum[blockIdx.x];
}
__global__ void k_setN(int* __restrict__ off, int N, int E){ off[N] = E; }
__global__ void k_fill(const int* __restrict__ ei, int E, const int* __restrict__ off,
                       int* __restrict__ cnt, int* __restrict__ lst){
  int e = blockIdx.x * blockDim.x + threadIdx.x;
  if (e >= E) return;
  int d = ei[E + e];
  int p = off[d] + atomicAdd(&cnt[d], 1);
  lst[p] = e;
}
__global__ void k_goff(const int* __restrict__ batch, int N, int G, int* __restrict__ goff){
  int g = blockIdx.x * blockDim.x + threadIdx.x;
  if (g > G) return;
  int lo = 0, hi = N;
  while (lo < hi){ int mid = (lo + hi) >> 1; if (batch[mid] < g) lo = mid + 1; else hi = mid; }
  goff[g] = lo;
}

// ---------------- fused GATEConv attention (online softmax, CSR) ----------
__global__ void k_gate_fused(const us* __restrict__ uh, const us* __restrict__ ul,
                             const float* __restrict__ T, const float* __restrict__ att_l,
                             const float* __restrict__ rvec,
                             const int* __restrict__ ei, const int* __restrict__ ea,
                             const int* __restrict__ off, const int* __restrict__ lst,
                             us* __restrict__ oh, us* __restrict__ ol, int N, int E){
  int d = (blockIdx.x * blockDim.x + threadIdx.x) >> 6;
  int lane = threadIdx.x & 63;
  if (d >= N) return;
  int beg = off[d], deg = off[d + 1] - beg;
  float rd = rvec[d];
  float accv[5] = {}, m = -1e30f, s = 0.f;
  for (int ii = 0; ii <= deg; ++ii){
    int src, c;
    if (ii < deg){ int e = lst[beg + ii]; src = ei[e]; c = ea[2*e] * 3 + ea[2*e + 1]; }
    else { src = d; c = 12; }                       // self-loop: bt=4,bd=0
    size_t ub = (size_t)src * KP;
    const float* Tc = T + c * D;
    float xj[5]; float part = 0.f;
    #pragma unroll
    for (int t = 0; t < 5; ++t){
      int j = lane + 64 * t;
      float v = 0.f;
      if (j < D){
        v = pread(uh, ul, ub + j) + Tc[j];
        v = v > 0.f ? v : 0.01f * v;
        part += v * att_l[j];
      }
      xj[t] = v;
    }
    #pragma unroll
    for (int o = 32; o; o >>= 1) part += __shfl_xor(part, o);
    float l = part + rd; l = l > 0.f ? l : 0.01f * l;
    float mn = fmaxf(m, l);
    float scale = expf(m - mn), p = expf(l - mn);
    #pragma unroll
    for (int t = 0; t < 5; ++t) accv[t] = accv[t] * scale + p * xj[t];
    s = s * scale + p; m = mn;
  }
  float inv = 1.f / (s + 1e-16f);
  #pragma unroll
  for (int t = 0; t < 5; ++t){
    int j = lane + 64 * t;
    if (j < KP) pwrite(oh, ol, (size_t)d * KP + j, j < D ? accv[t] * inv : 0.f);
  }
}

// ---------------- fused GATConv attention (+bias+elu) ---------------------
__global__ void k_gat_fused(const us* __restrict__ xh, const us* __restrict__ xl,
                            const float* __restrict__ as_, const float* __restrict__ ad,
                            const int* __restrict__ ei,
                            const int* __restrict__ off, const int* __restrict__ lst,
                            const float* __restrict__ bias,
                            us* __restrict__ oh, us* __restrict__ ol, int N, int E){
  int d = (blockIdx.x * blockDim.x + threadIdx.x) >> 6;
  int lane = threadIdx.x & 63;
  if (d >= N) return;
  int beg = off[d], deg = off[d + 1] - beg;
  float add = ad[d];
  float accv[5] = {}, m = -1e30f, s = 0.f;
  for (int ii = 0; ii < deg; ++ii){
    int e = lst[beg + ii];
    int src = ei[e];
    float l = as_[src] + add; l = l > 0.f ? l : 0.2f * l;
    float mn = fmaxf(m, l);
    float scale = expf(m - mn), p = expf(l - mn);
    size_t ub = (size_t)src * KP;
    #pragma unroll
    for (int t = 0; t < 5; ++t){
      int j = lane + 64 * t;
      float v = (j < D) ? pread(xh, xl, ub + j) : 0.f;
      accv[t] = accv[t] * scale + p * v;
    }
    s = s * scale + p; m = mn;
  }
  float inv = 1.f / (s + 1e-16f);
  #pragma unroll
  for (int t = 0; t < 5; ++t){
    int j = lane + 64 * t;
    if (j >= KP) continue;
    float v = 0.f;
    if (j < D){
      v = accv[t] * inv + bias[j];
      v = v > 0.f ? v : (expf(v) - 1.f);
    }
    pwrite(oh, ol, (size_t)d * KP + j, v);
  }
}

// ---------------- fused mol attention (+mol_b+elu), batch-sorted ranges ---
__global__ void k_mol_fused(const us* __restrict__ xh, const us* __restrict__ xl,
                            const float* __restrict__ asx, const float* __restrict__ adg,
                            const int* __restrict__ goff, const float* __restrict__ bias,
                            us* __restrict__ oh, us* __restrict__ ol, int G){
  int g = (blockIdx.x * blockDim.x + threadIdx.x) >> 6;
  int lane = threadIdx.x & 63;
  if (g >= G) return;
  int beg = goff[g], end = goff[g + 1];
  float add = adg[g];
  float accv[5] = {}, m = -1e30f, s = 0.f;
  for (int i = beg; i < end; ++i){
    float l = asx[i] + add; l = l > 0.f ? l : 0.2f * l;
    float mn = fmaxf(m, l);
    float scale = expf(m - mn), p = expf(l - mn);
    size_t ub = (size_t)i * KP;
    #pragma unroll
    for (int t = 0; t < 5; ++t){
      int j = lane + 64 * t;
      float v = (j < D) ? pread(xh, xl, ub + j) : 0.f;
      accv[t] = accv[t] * scale + p * v;
    }
    s = s * scale + p; m = mn;
  }
  float inv = 1.f / (s + 1e-16f);
  #pragma unroll
  for (int t = 0; t < 5; ++t){
    int j = lane + 64 * t;
    if (j >= KP) continue;
    float v = 0.f;
    if (j < D){
      v = accv[t] * inv + bias[j];
      v = v > 0.f ? v : (expf(v) - 1.f);
    }
    pwrite(oh, ol, (size_t)g * KP + j, v);
  }
}

// ---------------- segment-sum + relu -> G planes --------------------------
__global__ void k_gsum(const us* __restrict__ xh, const us* __restrict__ xl,
                       const int* __restrict__ goff,
                       us* __restrict__ oh, us* __restrict__ ol, int G){
  int g = (blockIdx.x * blockDim.x + threadIdx.x) >> 6;
  int lane = threadIdx.x & 63;
  if (g >= G) return;
  int beg = goff[g], end = goff[g + 1];
  float accv[5] = {};
  for (int i = beg; i < end; ++i){
    size_t ub = (size_t)i * KP;
    #pragma unroll
    for (int t = 0; t < 5; ++t){
      int j = lane + 64 * t;
      if (j < D) accv[t] += pread(xh, xl, ub + j);
    }
  }
  #pragma unroll
  for (int t = 0; t < 5; ++t){
    int j = lane + 64 * t;
    if (j < KP) pwrite(oh, ol, (size_t)g * KP + j, j < D ? fmaxf(accv[t], 0.f) : 0.f);
  }
}

// ---------------- final: out fp32 + pred ----------------------------------
__global__ void k_final2(const us* __restrict__ Oh, const us* __restrict__ Ol,
                         const float* __restrict__ w2, const float* __restrict__ b2,
                         float* __restrict__ out, int G){
  int g = (blockIdx.x * blockDim.x + threadIdx.x) >> 6;
  int lane = threadIdx.x & 63;
  if (g >= G) return;
  float s = 0.f;
  for (int j = lane; j < D; j += 64){
    float v = pread(Oh, Ol, (size_t)g * KP + j);
    out[(size_t)g * D + j] = v;
    s += v * w2[j];
  }
  #pragma unroll
  for (int o = 32; o; o >>= 1) s += __shfl_xor(s, o);
  if (lane == 0) out[(size_t)G * D + g] = s + b2[0];
}

// ===========================================================================
extern "C" void kernel_launch(void* const* d_in, const int* in_sizes, int n_in,
                              void* d_out, int out_size, void* d_ws, size_t ws_size,
                              hipStream_t stream){
  (void)n_in; (void)ws_size;
  const int*   x         = (const int*)d_in[0];
  const int*   ei        = (const int*)d_in[1];
  const int*   ea        = (const int*)d_in[2];
  const int*   batch     = (const int*)d_in[3];
  const float* emb_atom  = (const float*)d_in[4];
  const float* emb_chir  = (const float*)d_in[5];
  const float* lin1_W    = (const float*)d_in[6];
  const float* lin1_b    = (const float*)d_in[7];
  const float* ge_e1     = (const float*)d_in[8];
  const float* ge_e2     = (const float*)d_in[9];
  const float* ge_att_l  = (const float*)d_in[10];
  const float* ge_att_r  = (const float*)d_in[11];
  const float* ge_lin1_W = (const float*)d_in[12];
  const float* ge_lin2_W = (const float*)d_in[13];
  const float* ge_bias   = (const float*)d_in[14];
  const float* gat_W     = (const float*)d_in[15];
  const float* gat_att_s = (const float*)d_in[16];
  const float* gat_att_d = (const float*)d_in[17];
  const float* gat_b     = (const float*)d_in[18];
  const float* gru_wih   = (const float*)d_in[19];
  const float* gru_whh   = (const float*)d_in[20];
  const float* gru_bih   = (const float*)d_in[21];
  const float* gru_bhh   = (const float*)d_in[22];
  const float* mol_Ws    = (const float*)d_in[23];
  const float* mol_Wd    = (const float*)d_in[24];
  const float* mol_att_s = (const float*)d_in[25];
  const float* mol_att_d = (const float*)d_in[26];
  const float* mol_b     = (const float*)d_in[27];
  const float* mgru_wih  = (const float*)d_in[28];
  const float* mgru_whh  = (const float*)d_in[29];
  const float* mgru_bih  = (const float*)d_in[30];
  const float* mgru_bhh  = (const float*)d_in[31];
  const float* lin2_W    = (const float*)d_in[32];
  const float* lin2_b    = (const float*)d_in[33];

  const int N  = in_sizes[0] / 2;
  const int E  = in_sizes[1] / 2;
  const int G  = out_size / (D + 1);
  const int Npad = cdiv(N, 128) * 128;
  const int Gpad = cdiv(G, 128) * 128;

  char* base = (char*)d_ws;
  size_t used = 0;
  auto alloc = [&](size_t bytes) -> void* {
    void* p = base + used;
    used += (bytes + 255) & ~(size_t)255;
    return p;
  };
  // three N-row plane pairs
  us* PaH = (us*)alloc((size_t)Npad * KP * 2); us* PaL = (us*)alloc((size_t)Npad * KP * 2);
  us* PbH = (us*)alloc((size_t)Npad * KP * 2); us* PbL = (us*)alloc((size_t)Npad * KP * 2);
  us* PcH = (us*)alloc((size_t)Npad * KP * 2); us* PcL = (us*)alloc((size_t)Npad * KP * 2);
  // three G-row plane pairs
  us* QaH = (us*)alloc((size_t)Gpad * KP * 2); us* QaL = (us*)alloc((size_t)Gpad * KP * 2);
  us* QbH = (us*)alloc((size_t)Gpad * KP * 2); us* QbL = (us*)alloc((size_t)Gpad * KP * 2);
  us* QcH = (us*)alloc((size_t)Gpad * KP * 2); us* QcL = (us*)alloc((size_t)Gpad * KP * 2);
  // weights
  auto wsm = [&](void){ return (us*)alloc((size_t)384 * KP * 2); };
  auto wbg = [&](void){ return (us*)alloc((size_t)1024 * KP * 2); };
  us *wlin1H=wsm(), *wlin1L=wsm(), *wgeuH=wsm(), *wgeuL=wsm(), *wge2H=wsm(), *wge2L=wsm();
  us *wgatH[4], *wgatL[4];
  for (int l = 0; l < 4; ++l){ wgatH[l]=wsm(); wgatL[l]=wsm(); }
  us *wmolSH=wsm(), *wmolSL=wsm(), *wmolDH=wsm(), *wmolDL=wsm();
  us *wihH[5], *wihL[5], *whhH[5], *whhL[5];
  for (int l = 0; l < 5; ++l){ wihH[l]=wbg(); wihL[l]=wbg(); whhH[l]=wbg(); whhL[l]=wbg(); }
  us *wmgiH=wbg(), *wmgiL=wbg(), *wmghH=wbg(), *wmghL=wbg();
  float* Tt  = (float*)alloc(18 * D * 4);
  float* rv  = (float*)alloc((size_t)N * 4);
  float* adv = (float*)alloc((size_t)N * 4);
  float* asx = (float*)alloc((size_t)N * 4);
  // CSR
  const int SBS = 512;
  int nblk = cdiv(N, SBS);
  int* hist = (int*)alloc((size_t)N * 4);
  int* cnt  = (int*)alloc((size_t)N * 4);
  int* off  = (int*)alloc((size_t)(N + 1) * 4);
  int* bsum = (int*)alloc((size_t)nblk * 4);
  int* lst  = (int*)alloc((size_t)E * 4);
  int* goff = (int*)alloc((size_t)(G + 1) * 4);

  auto cvt2 = [&](const float* src, int ld, int M, us* hb, us* lb, int Mpad){
    int tot = Mpad * 80;
    k_cvt2<<<cdiv(tot, 256), 256, 0, stream>>>(src, ld, M, hb, lb, tot);
  };
  auto mm_p = [&](const us* ah, const us* al, const us* bh, const us* bl,
                  const float* bias, us* ch, us* cl, int M, int NC, int mode){
    dim3 grid(cdiv(NC, 128), cdiv(M, 128));
    if (mode == 0)      k_mfma3<0><<<grid, 256, 0, stream>>>(ah, al, bh, bl, bias, ch, cl, M, NC);
    else if (mode == 1) k_mfma3<1><<<grid, 256, 0, stream>>>(ah, al, bh, bl, bias, ch, cl, M, NC);
    else                k_mfma3<2><<<grid, 256, 0, stream>>>(ah, al, bh, bl, bias, ch, cl, M, NC);
  };
  auto gru = [&](const us* Ih, const us* Il, const us* Hh, const us* Hl,
                 const us* wiH, const us* wiL, const us* whH, const us* whL,
                 const float* bi, const float* bh, us* Oh, us* Ol, int Mpad){
    dim3 grid(19, Mpad / 128);
    k_gru<<<grid, 256, 0, stream>>>(Ih, Il, Hh, Hl, wiH, wiL, whH, whL, bi, bh, Oh, Ol);
  };

  // ---- CSR build ----
  hipMemsetAsync(hist, 0, (size_t)N * 4, stream);
  k_hist<<<cdiv(E, 256), 256, 0, stream>>>(ei, E, hist);
  k_scanA<SBS><<<nblk, SBS, 0, stream>>>(hist, off, bsum, N);
  k_scanB<SBS><<<1, SBS, 0, stream>>>(bsum, nblk);
  k_scanC<SBS><<<nblk, SBS, 0, stream>>>(off, bsum, N);
  k_setN<<<1, 1, 0, stream>>>(off, N, E);
  hipMemsetAsync(cnt, 0, (size_t)N * 4, stream);
  k_fill<<<cdiv(E, 256), 256, 0, stream>>>(ei, E, off, cnt, lst);
  k_goff<<<cdiv(G + 1, 256), 256, 0, stream>>>(batch, N, G, goff);

  // ---- weights -> planes ----
  cvt2(lin1_W, D, D, wlin1H, wlin1L, 384);
  cvt2(ge_lin1_W, 2 * D, D, wgeuH, wgeuL, 384);
  cvt2(ge_lin2_W, D, D, wge2H, wge2L, 384);
  for (int l = 0; l < 4; ++l) cvt2(gat_W + (size_t)l * D * D, D, D, wgatH[l], wgatL[l], 384);
  cvt2(mol_Ws, D, D, wmolSH, wmolSL, 384);
  cvt2(mol_Wd, D, D, wmolDH, wmolDL, 384);
  for (int l = 0; l < 5; ++l){
    cvt2(gru_wih + (size_t)l * 270000, D, 900, wihH[l], wihL[l], 1024);
    cvt2(gru_whh + (size_t)l * 270000, D, 900, whhH[l], whhL[l], 1024);
  }
  cvt2(mgru_wih, D, 900, wmgiH, wmgiL, 1024);
  cvt2(mgru_whh, D, 900, wmghH, wmghL, 1024);
  k_table<<<18, 256, 0, stream>>>(ge_e1, ge_e2, ge_lin1_W, Tt);

  // ---- init features ----
  k_embed2<<<cdiv(Npad * KP, 256), 256, 0, stream>>>(x, emb_atom, emb_chir, PaH, PaL, N, Npad * KP);
  mm_p(PaH, PaL, wlin1H, wlin1L, lin1_b, PbH, PbL, N, D, 1);       // xf -> Pb

  // ---- GATEConv ----
  mm_p(PbH, PbL, wgeuH, wgeuL, nullptr, PaH, PaL, N, D, 0);        // u -> Pa
  k_dot2<<<cdiv(N, 4), 256, 0, stream>>>(PbH, PbL, ge_att_r, rv, N);
  k_gate_fused<<<cdiv(N, 4), 256, 0, stream>>>(PaH, PaL, Tt, ge_att_l, rv,
                                               ei, ea, off, lst, PcH, PcL, N, E);
  mm_p(PcH, PcL, wge2H, wge2L, ge_bias, PaH, PaL, N, D, 2);        // elu(h) -> Pa
  gru(PaH, PaL, PbH, PbL, wihH[0], wihL[0], whhH[0], whhL[0],
      gru_bih, gru_bhh, PcH, PcL, Npad);                           // xf -> Pc

  us *xfH = PcH, *xfL = PcL, *aH = PaH, *aL = PaL, *bH = PbH, *bL = PbL;
  // ---- GATConv layers 1..4 ----
  for (int l = 0; l < 4; ++l){
    mm_p(xfH, xfL, wgatH[l], wgatL[l], nullptr, aH, aL, N, D, 0);  // xw -> a
    k_dot2<<<cdiv(N, 4), 256, 0, stream>>>(aH, aL, gat_att_s + l * D, rv, N);
    k_dot2<<<cdiv(N, 4), 256, 0, stream>>>(aH, aL, gat_att_d + l * D, adv, N);
    k_gat_fused<<<cdiv(N, 4), 256, 0, stream>>>(aH, aL, rv, adv, ei, off, lst,
                                                gat_b + l * D, bH, bL, N, E);
    gru(bH, bL, xfH, xfL, wihH[l+1], wihL[l+1], whhH[l+1], whhL[l+1],
        gru_bih + (l + 1) * 900, gru_bhh + (l + 1) * 900, aH, aL, Npad);  // xf' -> a
    us* th = xfH; us* tl = xfL;
    xfH = aH; xfL = aL; aH = th; aL = tl;
  }

  // ---- attentive readout ----
  k_gsum<<<cdiv(G, 4), 256, 0, stream>>>(xfH, xfL, goff, QaH, QaL, G);      // OUT -> Qa
  mm_p(xfH, xfL, wmolSH, wmolSL, nullptr, aH, aL, N, D, 0);                 // xs -> a (pinned)
  k_dot2<<<cdiv(N, 4), 256, 0, stream>>>(aH, aL, mol_att_s, asx, N);
  us *outH = QaH, *outL = QaL, *sgH = QbH, *sgL = QbL, *xdH = QcH, *xdL = QcL;
  for (int t = 0; t < 3; ++t){
    mm_p(outH, outL, wmolDH, wmolDL, nullptr, xdH, xdL, G, D, 0);           // xd
    k_dot2<<<cdiv(G, 4), 256, 0, stream>>>(xdH, xdL, mol_att_d, adv, G);
    k_mol_fused<<<cdiv(G, 4), 256, 0, stream>>>(aH, aL, asx, adv, goff, mol_b, sgH, sgL, G);
    gru(sgH, sgL, outH, outL, wmgiH, wmgiL, wmghH, wmghL,
        mgru_bih, mgru_bhh, xdH, xdL, Gpad);                                // out' -> xd
    us* th = outH; us* tl = outL;
    outH = xdH; outL = xdL; xdH = th; xdL = tl;
  }
  k_final2<<<cdiv(G, 4), 256, 0, stream>>>(outH, outL, lin2_W, lin2_b, (float*)d_out, G);
}

// Round 5
// 3950.165 us; speedup vs baseline: 2.6094x; 1.1292x over previous
//
#include <hip/hip_runtime.h>

constexpr int D = 300;
constexpr int KP = 320;   // K padded to multiple of 32

static inline int cdiv(int a, int b){ return (a + b - 1) / b; }

__device__ __forceinline__ unsigned short f2bf(float f){
  unsigned u = __float_as_uint(f);
  unsigned r = (u + 0x7fffu + ((u >> 16) & 1u)) >> 16;
  return (unsigned short)r;
}
__device__ __forceinline__ float bf2f(unsigned short h){
  return __uint_as_float((unsigned)h << 16);
}
__device__ __forceinline__ float pread(const unsigned short* __restrict__ h,
                                       const unsigned short* __restrict__ l, size_t i){
  return bf2f(h[i]) + bf2f(l[i]);
}
__device__ __forceinline__ void pwrite(unsigned short* __restrict__ h,
                                       unsigned short* __restrict__ l, size_t i, float v){
  unsigned short hi = f2bf(v);
  h[i] = hi; l[i] = f2bf(v - bf2f(hi));
}
// bijective XCD-chunk swizzle (m204): hardware bid -> chunked work id
__device__ __forceinline__ int xcd_chunk(int bid, int nwg){
  int q = nwg >> 3, r = nwg & 7;
  int x = bid & 7, i = bid >> 3;
  return (x < r ? x * (q + 1) : r * (q + 1) + (x - r) * q) + i;
}

typedef __attribute__((ext_vector_type(8))) short bf16x8;
typedef __attribute__((ext_vector_type(4))) float f32x4;
typedef unsigned short us;

// ------- fp32 [M x 300] (row stride ld) -> hi/lo bf16 planes [Mpad x 320] ---
__global__ void k_cvt2(const float* __restrict__ src, int ld, int M,
                       us* __restrict__ hb, us* __restrict__ lb, int total){
  int idx = blockIdx.x * blockDim.x + threadIdx.x;
  if (idx >= total) return;
  int r = idx / 80, k4 = (idx - r * 80) * 4;
  const float* row = src + (size_t)r * ld;
  bool rm = r < M;
  ushort4 oh, ol;
  float x;
  x = (rm && k4 + 0 < D) ? row[k4 + 0] : 0.f; oh.x = f2bf(x); ol.x = f2bf(x - bf2f(oh.x));
  x = (rm && k4 + 1 < D) ? row[k4 + 1] : 0.f; oh.y = f2bf(x); ol.y = f2bf(x - bf2f(oh.y));
  x = (rm && k4 + 2 < D) ? row[k4 + 2] : 0.f; oh.z = f2bf(x); ol.z = f2bf(x - bf2f(oh.z));
  x = (rm && k4 + 3 < D) ? row[k4 + 3] : 0.f; oh.w = f2bf(x); ol.w = f2bf(x - bf2f(oh.w));
  *(ushort4*)(hb + (size_t)r * KP + k4) = oh;
  *(ushort4*)(lb + (size_t)r * KP + k4) = ol;
}

// ------- GRU weight pack: [jt(10)][ks(10)][t(12)][kg(4)][row(32)][8 halves] --
// t = m*6 + g*2 + plane;  m: 0=Wih 1=Whh;  g: gate;  source fp32 [900][300]
__global__ void k_wpack(const float* __restrict__ Wih, const float* __restrict__ Whh,
                        us* __restrict__ out){
  int idx = blockIdx.x * blockDim.x + threadIdx.x;
  if (idx >= 307200) return;
  int h4 = idx * 4;
  int jtks = h4 / 12288;
  int within = h4 - jtks * 12288;
  int jt = jtks / 10, ks = jtks - (jtks / 10) * 10;
  int t = within >> 10;
  int w2 = within & 1023;
  int kg = w2 >> 8;
  int row = (w2 >> 3) & 31;
  int h0 = w2 & 7;
  int m = t / 6, g = (t >> 1) % 3, p = t & 1;
  int j = jt * 32 + row;
  const float* W = m ? Whh : Wih;
  ushort4 o;
  us* po = (us*)&o;
  #pragma unroll
  for (int u = 0; u < 4; ++u){
    int k = ks * 32 + kg * 8 + h0 + u;
    float v = (j < D && k < D) ? W[(size_t)(g * D + j) * D + k] : 0.f;
    us hi = f2bf(v);
    po[u] = p ? f2bf(v - bf2f(hi)) : hi;
  }
  *(ushort4*)(out + h4) = o;
}

// ------- bf16x3 MFMA gemm: planes = A @ B^T, A/B hi-lo plane pairs ---------
// 1D grid (rowTiles*3), XCD-chunked; MODE 0: none, 1: bias+leaky, 2: bias+elu
template<int MODE>
__global__ void k_mfma3(const us* __restrict__ Ah, const us* __restrict__ Al,
                        const us* __restrict__ Bh, const us* __restrict__ Bl,
                        const float* __restrict__ bias,
                        us* __restrict__ Ch, us* __restrict__ Cl,
                        int M, int NC){
  __shared__ short ls[4][4096];   // Ah,Al,Bh,Bl tiles: [kg(4)][row(128)][8]
  const int tid = threadIdx.x;
  const int lane = tid & 63;
  const int wid = tid >> 6, wr = wid >> 1, wc = wid & 1;
  int work = xcd_chunk(blockIdx.x, gridDim.x);
  const int rowBase = (work / 3) * 128, colBase = (work - (work / 3) * 3) * 128;
  const int l15 = lane & 15, l4 = lane >> 4;
  f32x4 acc[4][4] = {};
  const us* gsrc[4] = {Ah, Al, Bh, Bl};

  for (int k0 = 0; k0 < KP; k0 += 32){
    #pragma unroll
    for (int t = 0; t < 4; ++t){
      int base = (t < 2) ? rowBase : colBase;
      #pragma unroll
      for (int s = 0; s < 2; ++s){
        int lin = s * 256 + tid;
        int kg = lin >> 7, row = lin & 127;
        const us* g = gsrc[t] + (size_t)(base + row) * KP + k0 + kg * 8;
        short* lb = &ls[t][0] + (size_t)(s * 256 + (tid & ~63)) * 8;
        __builtin_amdgcn_global_load_lds((const __attribute__((address_space(1))) unsigned*)g,
                                         (__attribute__((address_space(3))) unsigned*)lb, 16, 0, 0);
      }
    }
    __syncthreads();
    bf16x8 fbh[4], fbl[4];
    #pragma unroll
    for (int j = 0; j < 4; ++j){
      int bi = l4 * 128 + wc * 64 + j * 16 + l15;
      fbh[j] = *(const bf16x8*)(&ls[2][0] + (size_t)bi * 8);
      fbl[j] = *(const bf16x8*)(&ls[3][0] + (size_t)bi * 8);
    }
    #pragma unroll
    for (int i = 0; i < 4; ++i){
      int ai = l4 * 128 + wr * 64 + i * 16 + l15;
      bf16x8 fah = *(const bf16x8*)(&ls[0][0] + (size_t)ai * 8);
      bf16x8 fal = *(const bf16x8*)(&ls[1][0] + (size_t)ai * 8);
      #pragma unroll
      for (int j = 0; j < 4; ++j){
        acc[i][j] = __builtin_amdgcn_mfma_f32_16x16x32_bf16(fah, fbh[j], acc[i][j], 0, 0, 0);
        acc[i][j] = __builtin_amdgcn_mfma_f32_16x16x32_bf16(fah, fbl[j], acc[i][j], 0, 0, 0);
        acc[i][j] = __builtin_amdgcn_mfma_f32_16x16x32_bf16(fal, fbh[j], acc[i][j], 0, 0, 0);
      }
    }
    __syncthreads();
  }

  #pragma unroll
  for (int i = 0; i < 4; ++i){
    #pragma unroll
    for (int q = 0; q < 4; ++q){
      int r = rowBase + wr * 64 + i * 16 + l4 * 4 + q;
      if (r >= M) continue;
      #pragma unroll
      for (int j = 0; j < 4; ++j){
        int c = colBase + wc * 64 + j * 16 + l15;
        if (c >= KP) continue;
        size_t o = (size_t)r * KP + c;
        if (c >= NC){ Ch[o] = 0; Cl[o] = 0; continue; }
        float v = acc[i][j][q];
        if (MODE) v += bias[c];
        if (MODE == 1) v = v > 0.f ? v : 0.01f * v;
        if (MODE == 2) v = v > 0.f ? v : (expf(v) - 1.f);
        pwrite(Ch, Cl, o, v);
      }
    }
  }
}

// ---------------- fully-fused GRU v2: 128 rows x 32 j's, packed weights ----
// 1D grid (rowTiles*10), XCD-chunked so a row-panel's 10 j-tiles share an XCD
__global__ __launch_bounds__(256) void k_gru(
    const us* __restrict__ Ih, const us* __restrict__ Il,
    const us* __restrict__ Hh, const us* __restrict__ Hl,
    const us* __restrict__ Wp,
    const float* __restrict__ bih, const float* __restrict__ bhh,
    us* __restrict__ Oh, us* __restrict__ Ol){
  __shared__ short lsA[4][4096];   // Ih,Il,Hh,Hl: [kg(4)][row(128)][8]
  __shared__ short lsW[12288];     // [t(12)][kg(4)][row(32)][8]
  const int tid = threadIdx.x, lane = tid & 63, wid = tid >> 6;
  const int l15 = lane & 15, l4 = lane >> 4;
  int work = xcd_chunk(blockIdx.x, gridDim.x);
  const int rt = work / 10, jt = work - rt * 10;
  const int rowBase = rt * 128;
  f32x4 acc[2][2][6] = {};
  const us* asrc[4] = {Ih, Il, Hh, Hl};

  for (int ks = 0; ks < 10; ++ks){
    int k0 = ks * 32;
    #pragma unroll
    for (int t = 0; t < 4; ++t){
      #pragma unroll
      for (int s = 0; s < 2; ++s){
        int lin = s * 256 + tid;
        const us* g = asrc[t] + (size_t)(rowBase + (lin & 127)) * KP + k0 + (lin >> 7) * 8;
        short* dst = &lsA[t][0] + (size_t)(s * 256 + (tid & ~63)) * 8;
        __builtin_amdgcn_global_load_lds((const __attribute__((address_space(1))) unsigned*)g,
                                         (__attribute__((address_space(3))) unsigned*)dst, 16, 0, 0);
      }
    }
    const us* wsrc = Wp + (size_t)(jt * 10 + ks) * 12288;
    #pragma unroll
    for (int s = 0; s < 6; ++s){
      int lin = s * 256 + tid;
      const us* g = wsrc + (size_t)lin * 8;
      short* dst = lsW + (size_t)(s * 256 + (tid & ~63)) * 8;
      __builtin_amdgcn_global_load_lds((const __attribute__((address_space(1))) unsigned*)g,
                                       (__attribute__((address_space(3))) unsigned*)dst, 16, 0, 0);
    }
    __syncthreads();
    bf16x8 fa[2][4];
    #pragma unroll
    for (int r = 0; r < 2; ++r){
      int ar = wid * 32 + r * 16 + l15;
      #pragma unroll
      for (int t = 0; t < 4; ++t)
        fa[r][t] = *(const bf16x8*)(&lsA[t][0] + (size_t)(l4 * 128 + ar) * 8);
    }
    #pragma unroll
    for (int c = 0; c < 2; ++c){
      #pragma unroll
      for (int mg = 0; mg < 6; ++mg){
        const int m = mg / 3, g = mg % 3;
        const int tH = m * 6 + g * 2;
        int wro = c * 16 + l15;
        bf16x8 wh = *(const bf16x8*)(lsW + (size_t)((tH * 4 + l4) * 32 + wro) * 8);
        bf16x8 wl = *(const bf16x8*)(lsW + (size_t)(((tH + 1) * 4 + l4) * 32 + wro) * 8);
        #pragma unroll
        for (int r = 0; r < 2; ++r){
          acc[r][c][mg] = __builtin_amdgcn_mfma_f32_16x16x32_bf16(fa[r][m*2],   wh, acc[r][c][mg], 0, 0, 0);
          acc[r][c][mg] = __builtin_amdgcn_mfma_f32_16x16x32_bf16(fa[r][m*2],   wl, acc[r][c][mg], 0, 0, 0);
          acc[r][c][mg] = __builtin_amdgcn_mfma_f32_16x16x32_bf16(fa[r][m*2+1], wh, acc[r][c][mg], 0, 0, 0);
        }
      }
    }
    __syncthreads();
  }

  #pragma unroll
  for (int c = 0; c < 2; ++c){
    int j = jt * 32 + c * 16 + l15;
    bool jok = j < D;
    float b0=0.f,b1=0.f,b2=0.f,c0=0.f,c1=0.f,c2=0.f;
    if (jok){ b0=bih[j]; b1=bih[j+300]; b2=bih[j+600]; c0=bhh[j]; c1=bhh[j+300]; c2=bhh[j+600]; }
    #pragma unroll
    for (int r = 0; r < 2; ++r){
      #pragma unroll
      for (int q = 0; q < 4; ++q){
        int row = rowBase + wid * 32 + r * 16 + l4 * 4 + q;
        float o = 0.f;
        if (jok){
          float ir = acc[r][c][0][q] + b0, iz = acc[r][c][1][q] + b1, in_ = acc[r][c][2][q] + b2;
          float hr = acc[r][c][3][q] + c0, hz = acc[r][c][4][q] + c1, hn  = acc[r][c][5][q] + c2;
          float rg = 1.f / (1.f + expf(-(ir + hr)));
          float zg = 1.f / (1.f + expf(-(iz + hz)));
          float nn = tanhf(in_ + rg * hn);
          float h = pread(Hh, Hl, (size_t)row * KP + j);
          o = (1.f - zg) * nn + zg * h;
          o = o > 0.f ? o : 0.f;
        }
        if (j < KP) pwrite(Oh, Ol, (size_t)row * KP + j, o);
      }
    }
  }
}

// ---------------- init: planes of emb_atom[x0]+emb_chir[x1] ----------------
__global__ void k_embed2(const int* __restrict__ x, const float* __restrict__ ea,
                         const float* __restrict__ ec, us* __restrict__ hb,
                         us* __restrict__ lb, int N, int total){
  int idx = blockIdx.x * blockDim.x + threadIdx.x;
  if (idx >= total) return;
  int r = idx / KP, j = idx - r * KP;
  float v = (r < N && j < D) ? ea[x[2*r] * D + j] + ec[x[2*r+1] * D + j] : 0.f;
  pwrite(hb, lb, idx, v);
}

// ---------------- T[c] = (ge_e1[t]+ge_e2[d]) @ W1b^T (18 combos, fp32) ----
__global__ void k_table(const float* __restrict__ e1, const float* __restrict__ e2,
                        const float* __restrict__ W1, float* __restrict__ T){
  int c = blockIdx.x, t = c / 3, d = c - 3 * (c / 3);
  __shared__ float se[D];
  for (int k = threadIdx.x; k < D; k += blockDim.x) se[k] = e1[t*D + k] + e2[d*D + k];
  __syncthreads();
  for (int j = threadIdx.x; j < D; j += blockDim.x){
    float s = 0.f;
    for (int k = 0; k < D; ++k) s += se[k] * W1[(size_t)j * 600 + 300 + k];
    T[c*D + j] = s;
  }
}

// ---------------- row dot (plane pair) ------------------------------------
__global__ void k_dot2(const us* __restrict__ Ahp, const us* __restrict__ Alp,
                       const float* __restrict__ v, float* __restrict__ out, int M){
  int w = (blockIdx.x * blockDim.x + threadIdx.x) >> 6;
  int lane = threadIdx.x & 63;
  if (w >= M) return;
  size_t base = (size_t)w * KP;
  float s = 0.f;
  for (int j = lane; j < D; j += 64) s += pread(Ahp, Alp, base + j) * v[j];
  #pragma unroll
  for (int o = 32; o; o >>= 1) s += __shfl_xor(s, o);
  if (lane == 0) out[w] = s;
}

// ---------------- CSR build ------------------------------------------------
__global__ void k_hist(const int* __restrict__ ei, int E, int* __restrict__ hist){
  int e = blockIdx.x * blockDim.x + threadIdx.x;
  if (e < E) atomicAdd(&hist[ei[E + e]], 1);
}
template<int BS>
__global__ void k_scanA(const int* __restrict__ in, int* __restrict__ out,
                        int* __restrict__ bsum, int n){
  __shared__ int s[BS];
  int t = threadIdx.x, gid = blockIdx.x * BS + t;
  int v = (gid < n) ? in[gid] : 0;
  s[t] = v; __syncthreads();
  for (int o = 1; o < BS; o <<= 1){
    int add = (t >= o) ? s[t - o] : 0;
    __syncthreads();
    s[t] += add;
    __syncthreads();
  }
  if (gid < n) out[gid] = s[t] - v;
  if (t == BS - 1) bsum[blockIdx.x] = s[BS - 1];
}
template<int BS>
__global__ void k_scanB(int* __restrict__ bsum, int nb){
  __shared__ int s[BS];
  int t = threadIdx.x;
  int v = (t < nb) ? bsum[t] : 0;
  s[t] = v; __syncthreads();
  for (int o = 1; o < BS; o <<= 1){
    int add = (t >= o) ? s[t - o] : 0;
    __syncthreads();
    s[t] += add;
    __syncthreads();
  }
  if (t < nb) bsum[t] = s[t] - v;
}
template<int BS>
__global__ void k_scanC(int* __restrict__ out, const int* __restrict__ bsum, int n){
  int gid = blockIdx.x * BS + threadIdx.x;
  if (gid < n) out[gid] += bsum[blockIdx.x];
}
__global__ void k_setN(int* __restrict__ off, int N, int E){ off[N] = E; }
__global__ void k_fill(const int* __restrict__ ei, int E, const int* __restrict__ off,
                       int* __restrict__ cnt, int* __restrict__ lst){
  int e = blockIdx.x * blockDim.x + threadIdx.x;
  if (e >= E) return;
  int d = ei[E + e];
  int p = off[d] + atomicAdd(&cnt[d], 1);
  lst[p] = e;
}
__global__ void k_goff(const int* __restrict__ batch, int N, int G, int* __restrict__ goff){
  int g = blockIdx.x * blockDim.x + threadIdx.x;
  if (g > G) return;
  int lo = 0, hi = N;
  while (lo < hi){ int mid = (lo + hi) >> 1; if (batch[mid] < g) lo = mid + 1; else hi = mid; }
  goff[g] = lo;
}

// ---------------- fused GATEConv attention (online softmax, CSR) ----------
__global__ void k_gate_fused(const us* __restrict__ uh, const us* __restrict__ ul,
                             const float* __restrict__ T, const float* __restrict__ att_l,
                             const float* __restrict__ rvec,
                             const int* __restrict__ ei, const int* __restrict__ ea,
                             const int* __restrict__ off, const int* __restrict__ lst,
                             us* __restrict__ oh, us* __restrict__ ol, int N, int E){
  int d = (blockIdx.x * blockDim.x + threadIdx.x) >> 6;
  int lane = threadIdx.x & 63;
  if (d >= N) return;
  int beg = off[d], deg = off[d + 1] - beg;
  float rd = rvec[d];
  float accv[5] = {}, m = -1e30f, s = 0.f;
  for (int ii = 0; ii <= deg; ++ii){
    int src, c;
    if (ii < deg){ int e = lst[beg + ii]; src = ei[e]; c = ea[2*e] * 3 + ea[2*e + 1]; }
    else { src = d; c = 12; }                       // self-loop: bt=4,bd=0
    size_t ub = (size_t)src * KP;
    const float* Tc = T + c * D;
    float xj[5]; float part = 0.f;
    #pragma unroll
    for (int t = 0; t < 5; ++t){
      int j = lane + 64 * t;
      float v = 0.f;
      if (j < D){
        v = pread(uh, ul, ub + j) + Tc[j];
        v = v > 0.f ? v : 0.01f * v;
        part += v * att_l[j];
      }
      xj[t] = v;
    }
    #pragma unroll
    for (int o = 32; o; o >>= 1) part += __shfl_xor(part, o);
    float l = part + rd; l = l > 0.f ? l : 0.01f * l;
    float mn = fmaxf(m, l);
    float scale = expf(m - mn), p = expf(l - mn);
    #pragma unroll
    for (int t = 0; t < 5; ++t) accv[t] = accv[t] * scale + p * xj[t];
    s = s * scale + p; m = mn;
  }
  float inv = 1.f / (s + 1e-16f);
  #pragma unroll
  for (int t = 0; t < 5; ++t){
    int j = lane + 64 * t;
    if (j < KP) pwrite(oh, ol, (size_t)d * KP + j, j < D ? accv[t] * inv : 0.f);
  }
}

// ---------------- fused GATConv attention (+bias+elu) ---------------------
__global__ void k_gat_fused(const us* __restrict__ xh, const us* __restrict__ xl,
                            const float* __restrict__ as_, const float* __restrict__ ad,
                            const int* __restrict__ ei,
                            const int* __restrict__ off, const int* __restrict__ lst,
                            const float* __restrict__ bias,
                            us* __restrict__ oh, us* __restrict__ ol, int N, int E){
  int d = (blockIdx.x * blockDim.x + threadIdx.x) >> 6;
  int lane = threadIdx.x & 63;
  if (d >= N) return;
  int beg = off[d], deg = off[d + 1] - beg;
  float add = ad[d];
  float accv[5] = {}, m = -1e30f, s = 0.f;
  for (int ii = 0; ii < deg; ++ii){
    int e = lst[beg + ii];
    int src = ei[e];
    float l = as_[src] + add; l = l > 0.f ? l : 0.2f * l;
    float mn = fmaxf(m, l);
    float scale = expf(m - mn), p = expf(l - mn);
    size_t ub = (size_t)src * KP;
    #pragma unroll
    for (int t = 0; t < 5; ++t){
      int j = lane + 64 * t;
      float v = (j < D) ? pread(xh, xl, ub + j) : 0.f;
      accv[t] = accv[t] * scale + p * v;
    }
    s = s * scale + p; m = mn;
  }
  float inv = 1.f / (s + 1e-16f);
  #pragma unroll
  for (int t = 0; t < 5; ++t){
    int j = lane + 64 * t;
    if (j >= KP) continue;
    float v = 0.f;
    if (j < D){
      v = accv[t] * inv + bias[j];
      v = v > 0.f ? v : (expf(v) - 1.f);
    }
    pwrite(oh, ol, (size_t)d * KP + j, v);
  }
}

// ---------------- fused mol attention (+mol_b+elu), batch-sorted ranges ---
__global__ void k_mol_fused(const us* __restrict__ xh, const us* __restrict__ xl,
                            const float* __restrict__ asx, const float* __restrict__ adg,
                            const int* __restrict__ goff, const float* __restrict__ bias,
                            us* __restrict__ oh, us* __restrict__ ol, int G){
  int g = (blockIdx.x * blockDim.x + threadIdx.x) >> 6;
  int lane = threadIdx.x & 63;
  if (g >= G) return;
  int beg = goff[g], end = goff[g + 1];
  float add = adg[g];
  float accv[5] = {}, m = -1e30f, s = 0.f;
  for (int i = beg; i < end; ++i){
    float l = asx[i] + add; l = l > 0.f ? l : 0.2f * l;
    float mn = fmaxf(m, l);
    float scale = expf(m - mn), p = expf(l - mn);
    size_t ub = (size_t)i * KP;
    #pragma unroll
    for (int t = 0; t < 5; ++t){
      int j = lane + 64 * t;
      float v = (j < D) ? pread(xh, xl, ub + j) : 0.f;
      accv[t] = accv[t] * scale + p * v;
    }
    s = s * scale + p; m = mn;
  }
  float inv = 1.f / (s + 1e-16f);
  #pragma unroll
  for (int t = 0; t < 5; ++t){
    int j = lane + 64 * t;
    if (j >= KP) continue;
    float v = 0.f;
    if (j < D){
      v = accv[t] * inv + bias[j];
      v = v > 0.f ? v : (expf(v) - 1.f);
    }
    pwrite(oh, ol, (size_t)g * KP + j, v);
  }
}

// ---------------- segment-sum + relu -> G planes --------------------------
__global__ void k_gsum(const us* __restrict__ xh, const us* __restrict__ xl,
                       const int* __restrict__ goff,
                       us* __restrict__ oh, us* __restrict__ ol, int G){
  int g = (blockIdx.x * blockDim.x + threadIdx.x) >> 6;
  int lane = threadIdx.x & 63;
  if (g >= G) return;
  int beg = goff[g], end = goff[g + 1];
  float accv[5] = {};
  for (int i = beg; i < end; ++i){
    size_t ub = (size_t)i * KP;
    #pragma unroll
    for (int t = 0; t < 5; ++t){
      int j = lane + 64 * t;
      if (j < D) accv[t] += pread(xh, xl, ub + j);
    }
  }
  #pragma unroll
  for (int t = 0; t < 5; ++t){
    int j = lane + 64 * t;
    if (j < KP) pwrite(oh, ol, (size_t)g * KP + j, j < D ? fmaxf(accv[t], 0.f) : 0.f);
  }
}

// ---------------- final: out fp32 + pred ----------------------------------
__global__ void k_final2(const us* __restrict__ Oh, const us* __restrict__ Ol,
                         const float* __restrict__ w2, const float* __restrict__ b2,
                         float* __restrict__ out, int G){
  int g = (blockIdx.x * blockDim.x + threadIdx.x) >> 6;
  int lane = threadIdx.x & 63;
  if (g >= G) return;
  float s = 0.f;
  for (int j = lane; j < D; j += 64){
    float v = pread(Oh, Ol, (size_t)g * KP + j);
    out[(size_t)g * D + j] = v;
    s += v * w2[j];
  }
  #pragma unroll
  for (int o = 32; o; o >>= 1) s += __shfl_xor(s, o);
  if (lane == 0) out[(size_t)G * D + g] = s + b2[0];
}

// ===========================================================================
extern "C" void kernel_launch(void* const* d_in, const int* in_sizes, int n_in,
                              void* d_out, int out_size, void* d_ws, size_t ws_size,
                              hipStream_t stream){
  (void)n_in; (void)ws_size;
  const int*   x         = (const int*)d_in[0];
  const int*   ei        = (const int*)d_in[1];
  const int*   ea        = (const int*)d_in[2];
  const int*   batch     = (const int*)d_in[3];
  const float* emb_atom  = (const float*)d_in[4];
  const float* emb_chir  = (const float*)d_in[5];
  const float* lin1_W    = (const float*)d_in[6];
  const float* lin1_b    = (const float*)d_in[7];
  const float* ge_e1     = (const float*)d_in[8];
  const float* ge_e2     = (const float*)d_in[9];
  const float* ge_att_l  = (const float*)d_in[10];
  const float* ge_att_r  = (const float*)d_in[11];
  const float* ge_lin1_W = (const float*)d_in[12];
  const float* ge_lin2_W = (const float*)d_in[13];
  const float* ge_bias   = (const float*)d_in[14];
  const float* gat_W     = (const float*)d_in[15];
  const float* gat_att_s = (const float*)d_in[16];
  const float* gat_att_d = (const float*)d_in[17];
  const float* gat_b     = (const float*)d_in[18];
  const float* gru_wih   = (const float*)d_in[19];
  const float* gru_whh   = (const float*)d_in[20];
  const float* gru_bih   = (const float*)d_in[21];
  const float* gru_bhh   = (const float*)d_in[22];
  const float* mol_Ws    = (const float*)d_in[23];
  const float* mol_Wd    = (const float*)d_in[24];
  const float* mol_att_s = (const float*)d_in[25];
  const float* mol_att_d = (const float*)d_in[26];
  const float* mol_b     = (const float*)d_in[27];
  const float* mgru_wih  = (const float*)d_in[28];
  const float* mgru_whh  = (const float*)d_in[29];
  const float* mgru_bih  = (const float*)d_in[30];
  const float* mgru_bhh  = (const float*)d_in[31];
  const float* lin2_W    = (const float*)d_in[32];
  const float* lin2_b    = (const float*)d_in[33];

  const int N  = in_sizes[0] / 2;
  const int E  = in_sizes[1] / 2;
  const int G  = out_size / (D + 1);
  const int Npad = cdiv(N, 128) * 128;
  const int Gpad = cdiv(G, 128) * 128;

  char* base = (char*)d_ws;
  size_t used = 0;
  auto alloc = [&](size_t bytes) -> void* {
    void* p = base + used;
    used += (bytes + 255) & ~(size_t)255;
    return p;
  };
  // three N-row plane pairs
  us* PaH = (us*)alloc((size_t)Npad * KP * 2); us* PaL = (us*)alloc((size_t)Npad * KP * 2);
  us* PbH = (us*)alloc((size_t)Npad * KP * 2); us* PbL = (us*)alloc((size_t)Npad * KP * 2);
  us* PcH = (us*)alloc((size_t)Npad * KP * 2); us* PcL = (us*)alloc((size_t)Npad * KP * 2);
  // three G-row plane pairs
  us* QaH = (us*)alloc((size_t)Gpad * KP * 2); us* QaL = (us*)alloc((size_t)Gpad * KP * 2);
  us* QbH = (us*)alloc((size_t)Gpad * KP * 2); us* QbL = (us*)alloc((size_t)Gpad * KP * 2);
  us* QcH = (us*)alloc((size_t)Gpad * KP * 2); us* QcL = (us*)alloc((size_t)Gpad * KP * 2);
  // small weights (plane pairs, 384 rows)
  auto wsm = [&](void){ return (us*)alloc((size_t)384 * KP * 2); };
  us *wlin1H=wsm(), *wlin1L=wsm(), *wgeuH=wsm(), *wgeuL=wsm(), *wge2H=wsm(), *wge2L=wsm();
  us *wgatH[4], *wgatL[4];
  for (int l = 0; l < 4; ++l){ wgatH[l]=wsm(); wgatL[l]=wsm(); }
  us *wmolSH=wsm(), *wmolSL=wsm(), *wmolDH=wsm(), *wmolDL=wsm();
  // packed GRU weights: 6 sets (5 atom GRUs + 1 mol GRU)
  us* Wgru[6];
  for (int l = 0; l < 6; ++l) Wgru[l] = (us*)alloc((size_t)1228800 * 2);
  float* Tt  = (float*)alloc(18 * D * 4);
  float* rv  = (float*)alloc((size_t)N * 4);
  float* adv = (float*)alloc((size_t)N * 4);
  float* asx = (float*)alloc((size_t)N * 4);
  // CSR
  const int SBS = 512;
  int nblk = cdiv(N, SBS);
  int* hist = (int*)alloc((size_t)N * 4);
  int* cnt  = (int*)alloc((size_t)N * 4);
  int* off  = (int*)alloc((size_t)(N + 1) * 4);
  int* bsum = (int*)alloc((size_t)nblk * 4);
  int* lst  = (int*)alloc((size_t)E * 4);
  int* goff = (int*)alloc((size_t)(G + 1) * 4);

  auto cvt2 = [&](const float* src, int ld, int M, us* hb, us* lb, int Mpad){
    int tot = Mpad * 80;
    k_cvt2<<<cdiv(tot, 256), 256, 0, stream>>>(src, ld, M, hb, lb, tot);
  };
  auto mm_p = [&](const us* ah, const us* al, const us* bh, const us* bl,
                  const float* bias, us* ch, us* cl, int M, int NC, int mode){
    int nwg = cdiv(M, 128) * 3;
    if (mode == 0)      k_mfma3<0><<<nwg, 256, 0, stream>>>(ah, al, bh, bl, bias, ch, cl, M, NC);
    else if (mode == 1) k_mfma3<1><<<nwg, 256, 0, stream>>>(ah, al, bh, bl, bias, ch, cl, M, NC);
    else                k_mfma3<2><<<nwg, 256, 0, stream>>>(ah, al, bh, bl, bias, ch, cl, M, NC);
  };
  auto gru = [&](const us* Ih, const us* Il, const us* Hh, const us* Hl,
                 const us* Wp, const float* bi, const float* bh,
                 us* Oh, us* Ol, int Mpad){
    int nwg = (Mpad / 128) * 10;
    k_gru<<<nwg, 256, 0, stream>>>(Ih, Il, Hh, Hl, Wp, bi, bh, Oh, Ol);
  };

  // ---- CSR build ----
  hipMemsetAsync(hist, 0, (size_t)N * 4, stream);
  k_hist<<<cdiv(E, 256), 256, 0, stream>>>(ei, E, hist);
  k_scanA<SBS><<<nblk, SBS, 0, stream>>>(hist, off, bsum, N);
  k_scanB<SBS><<<1, SBS, 0, stream>>>(bsum, nblk);
  k_scanC<SBS><<<nblk, SBS, 0, stream>>>(off, bsum, N);
  k_setN<<<1, 1, 0, stream>>>(off, N, E);
  hipMemsetAsync(cnt, 0, (size_t)N * 4, stream);
  k_fill<<<cdiv(E, 256), 256, 0, stream>>>(ei, E, off, cnt, lst);
  k_goff<<<cdiv(G + 1, 256), 256, 0, stream>>>(batch, N, G, goff);

  // ---- weights -> planes / packs ----
  cvt2(lin1_W, D, D, wlin1H, wlin1L, 384);
  cvt2(ge_lin1_W, 2 * D, D, wgeuH, wgeuL, 384);
  cvt2(ge_lin2_W, D, D, wge2H, wge2L, 384);
  for (int l = 0; l < 4; ++l) cvt2(gat_W + (size_t)l * D * D, D, D, wgatH[l], wgatL[l], 384);
  cvt2(mol_Ws, D, D, wmolSH, wmolSL, 384);
  cvt2(mol_Wd, D, D, wmolDH, wmolDL, 384);
  for (int l = 0; l < 5; ++l)
    k_wpack<<<1200, 256, 0, stream>>>(gru_wih + (size_t)l * 270000,
                                      gru_whh + (size_t)l * 270000, Wgru[l]);
  k_wpack<<<1200, 256, 0, stream>>>(mgru_wih, mgru_whh, Wgru[5]);
  k_table<<<18, 256, 0, stream>>>(ge_e1, ge_e2, ge_lin1_W, Tt);

  // ---- init features ----
  k_embed2<<<cdiv(Npad * KP, 256), 256, 0, stream>>>(x, emb_atom, emb_chir, PaH, PaL, N, Npad * KP);
  mm_p(PaH, PaL, wlin1H, wlin1L, lin1_b, PbH, PbL, N, D, 1);       // xf -> Pb

  // ---- GATEConv ----
  mm_p(PbH, PbL, wgeuH, wgeuL, nullptr, PaH, PaL, N, D, 0);        // u -> Pa
  k_dot2<<<cdiv(N, 4), 256, 0, stream>>>(PbH, PbL, ge_att_r, rv, N);
  k_gate_fused<<<cdiv(N, 4), 256, 0, stream>>>(PaH, PaL, Tt, ge_att_l, rv,
                                               ei, ea, off, lst, PcH, PcL, N, E);
  mm_p(PcH, PcL, wge2H, wge2L, ge_bias, PaH, PaL, N, D, 2);        // elu(h) -> Pa
  gru(PaH, PaL, PbH, PbL, Wgru[0], gru_bih, gru_bhh, PcH, PcL, Npad);   // xf -> Pc

  us *xfH = PcH, *xfL = PcL, *aH = PaH, *aL = PaL, *bH = PbH, *bL = PbL;
  // ---- GATConv layers 1..4 ----
  for (int l = 0; l < 4; ++l){
    mm_p(xfH, xfL, wgatH[l], wgatL[l], nullptr, aH, aL, N, D, 0);  // xw -> a
    k_dot2<<<cdiv(N, 4), 256, 0, stream>>>(aH, aL, gat_att_s + l * D, rv, N);
    k_dot2<<<cdiv(N, 4), 256, 0, stream>>>(aH, aL, gat_att_d + l * D, adv, N);
    k_gat_fused<<<cdiv(N, 4), 256, 0, stream>>>(aH, aL, rv, adv, ei, off, lst,
                                                gat_b + l * D, bH, bL, N, E);
    gru(bH, bL, xfH, xfL, Wgru[l + 1],
        gru_bih + (l + 1) * 900, gru_bhh + (l + 1) * 900, aH, aL, Npad);  // xf' -> a
    us* th = xfH; us* tl = xfL;
    xfH = aH; xfL = aL; aH = th; aL = tl;
  }

  // ---- attentive readout ----
  k_gsum<<<cdiv(G, 4), 256, 0, stream>>>(xfH, xfL, goff, QaH, QaL, G);      // OUT -> Qa
  mm_p(xfH, xfL, wmolSH, wmolSL, nullptr, aH, aL, N, D, 0);                 // xs -> a (pinned)
  k_dot2<<<cdiv(N, 4), 256, 0, stream>>>(aH, aL, mol_att_s, asx, N);
  us *outH = QaH, *outL = QaL, *sgH = QbH, *sgL = QbL, *xdH = QcH, *xdL = QcL;
  for (int t = 0; t < 3; ++t){
    mm_p(outH, outL, wmolDH, wmolDL, nullptr, xdH, xdL, G, D, 0);           // xd
    k_dot2<<<cdiv(G, 4), 256, 0, stream>>>(xdH, xdL, mol_att_d, adv, G);
    k_mol_fused<<<cdiv(G, 4), 256, 0, stream>>>(aH, aL, asx, adv, goff, mol_b, sgH, sgL, G);
    gru(sgH, sgL, outH, outL, Wgru[5], mgru_bih, mgru_bhh, xdH, xdL, Gpad); // out' -> xd
    us* th = outH; us* tl = outL;
    outH = xdH; outL = xdL; xdH = th; xdL = tl;
  }
  k_final2<<<cdiv(G, 4), 256, 0, stream>>>(outH, outL, lin2_W, lin2_b, (float*)d_out, G);
}

// Round 6
// 2857.028 us; speedup vs baseline: 3.6078x; 1.3826x over previous
//
#include <hip/hip_runtime.h>

constexpr int D = 300;
constexpr int KP = 320;   // K padded to multiple of 32

static inline int cdiv(int a, int b){ return (a + b - 1) / b; }

__device__ __forceinline__ unsigned short f2bf(float f){
  unsigned u = __float_as_uint(f);
  unsigned r = (u + 0x7fffu + ((u >> 16) & 1u)) >> 16;
  return (unsigned short)r;
}
__device__ __forceinline__ float bf2f(unsigned short h){
  return __uint_as_float((unsigned)h << 16);
}
__device__ __forceinline__ float pread(const unsigned short* __restrict__ h,
                                       const unsigned short* __restrict__ l, size_t i){
  return bf2f(h[i]) + bf2f(l[i]);
}
__device__ __forceinline__ void pwrite(unsigned short* __restrict__ h,
                                       unsigned short* __restrict__ l, size_t i, float v){
  unsigned short hi = f2bf(v);
  h[i] = hi; l[i] = f2bf(v - bf2f(hi));
}
// bijective XCD-chunk swizzle (m204): hardware bid -> chunked work id
__device__ __forceinline__ int xcd_chunk(int bid, int nwg){
  int q = nwg >> 3, r = nwg & 7;
  int x = bid & 7, i = bid >> 3;
  return (x < r ? x * (q + 1) : r * (q + 1) + (x - r) * q) + i;
}

typedef __attribute__((ext_vector_type(8))) short bf16x8;
typedef __attribute__((ext_vector_type(4))) float f32x4;
typedef unsigned short us;

// ------- fp32 [M x 300] (row stride ld) -> hi/lo bf16 planes [Mpad x 320] ---
__global__ void k_cvt2(const float* __restrict__ src, int ld, int M,
                       us* __restrict__ hb, us* __restrict__ lb, int total){
  int idx = blockIdx.x * blockDim.x + threadIdx.x;
  if (idx >= total) return;
  int r = idx / 80, k4 = (idx - r * 80) * 4;
  const float* row = src + (size_t)r * ld;
  bool rm = r < M;
  ushort4 oh, ol;
  float x;
  x = (rm && k4 + 0 < D) ? row[k4 + 0] : 0.f; oh.x = f2bf(x); ol.x = f2bf(x - bf2f(oh.x));
  x = (rm && k4 + 1 < D) ? row[k4 + 1] : 0.f; oh.y = f2bf(x); ol.y = f2bf(x - bf2f(oh.y));
  x = (rm && k4 + 2 < D) ? row[k4 + 2] : 0.f; oh.z = f2bf(x); ol.z = f2bf(x - bf2f(oh.z));
  x = (rm && k4 + 3 < D) ? row[k4 + 3] : 0.f; oh.w = f2bf(x); ol.w = f2bf(x - bf2f(oh.w));
  *(ushort4*)(hb + (size_t)r * KP + k4) = oh;
  *(ushort4*)(lb + (size_t)r * KP + k4) = ol;
}

// ------- GRU weight pack: [jt(10)][ks(10)][t(12)][kg(4)][row(32)][8 halves] --
__global__ void k_wpack(const float* __restrict__ Wih, const float* __restrict__ Whh,
                        us* __restrict__ out){
  int idx = blockIdx.x * blockDim.x + threadIdx.x;
  if (idx >= 307200) return;
  int h4 = idx * 4;
  int jtks = h4 / 12288;
  int within = h4 - jtks * 12288;
  int jt = jtks / 10, ks = jtks - (jtks / 10) * 10;
  int t = within >> 10;
  int w2 = within & 1023;
  int kg = w2 >> 8;
  int row = (w2 >> 3) & 31;
  int h0 = w2 & 7;
  int m = t / 6, g = (t >> 1) % 3, p = t & 1;
  int j = jt * 32 + row;
  const float* W = m ? Whh : Wih;
  ushort4 o;
  us* po = (us*)&o;
  #pragma unroll
  for (int u = 0; u < 4; ++u){
    int k = ks * 32 + kg * 8 + h0 + u;
    float v = (j < D && k < D) ? W[(size_t)(g * D + j) * D + k] : 0.f;
    us hi = f2bf(v);
    po[u] = p ? f2bf(v - bf2f(hi)) : hi;
  }
  *(ushort4*)(out + h4) = o;
}

// ------- bf16x3 MFMA gemm: planes = A @ B^T, A/B hi-lo plane pairs ---------
template<int MODE>
__global__ void k_mfma3(const us* __restrict__ Ah, const us* __restrict__ Al,
                        const us* __restrict__ Bh, const us* __restrict__ Bl,
                        const float* __restrict__ bias,
                        us* __restrict__ Ch, us* __restrict__ Cl,
                        int M, int NC){
  __shared__ short ls[4][4096];   // Ah,Al,Bh,Bl tiles: [kg(4)][row(128)][8]
  const int tid = threadIdx.x;
  const int lane = tid & 63;
  const int wid = tid >> 6, wr = wid >> 1, wc = wid & 1;
  int work = xcd_chunk(blockIdx.x, gridDim.x);
  const int rowBase = (work / 3) * 128, colBase = (work - (work / 3) * 3) * 128;
  const int l15 = lane & 15, l4 = lane >> 4;
  f32x4 acc[4][4] = {};
  const us* gsrc[4] = {Ah, Al, Bh, Bl};

  for (int k0 = 0; k0 < KP; k0 += 32){
    #pragma unroll
    for (int t = 0; t < 4; ++t){
      int base = (t < 2) ? rowBase : colBase;
      #pragma unroll
      for (int s = 0; s < 2; ++s){
        int lin = s * 256 + tid;
        int kg = lin >> 7, row = lin & 127;
        const us* g = gsrc[t] + (size_t)(base + row) * KP + k0 + kg * 8;
        short* lb = &ls[t][0] + (size_t)(s * 256 + (tid & ~63)) * 8;
        __builtin_amdgcn_global_load_lds((const __attribute__((address_space(1))) unsigned*)g,
                                         (__attribute__((address_space(3))) unsigned*)lb, 16, 0, 0);
      }
    }
    __syncthreads();
    bf16x8 fbh[4], fbl[4];
    #pragma unroll
    for (int j = 0; j < 4; ++j){
      int bi = l4 * 128 + wc * 64 + j * 16 + l15;
      fbh[j] = *(const bf16x8*)(&ls[2][0] + (size_t)bi * 8);
      fbl[j] = *(const bf16x8*)(&ls[3][0] + (size_t)bi * 8);
    }
    #pragma unroll
    for (int i = 0; i < 4; ++i){
      int ai = l4 * 128 + wr * 64 + i * 16 + l15;
      bf16x8 fah = *(const bf16x8*)(&ls[0][0] + (size_t)ai * 8);
      bf16x8 fal = *(const bf16x8*)(&ls[1][0] + (size_t)ai * 8);
      #pragma unroll
      for (int j = 0; j < 4; ++j){
        acc[i][j] = __builtin_amdgcn_mfma_f32_16x16x32_bf16(fah, fbh[j], acc[i][j], 0, 0, 0);
        acc[i][j] = __builtin_amdgcn_mfma_f32_16x16x32_bf16(fah, fbl[j], acc[i][j], 0, 0, 0);
        acc[i][j] = __builtin_amdgcn_mfma_f32_16x16x32_bf16(fal, fbh[j], acc[i][j], 0, 0, 0);
      }
    }
    __syncthreads();
  }

  #pragma unroll
  for (int i = 0; i < 4; ++i){
    #pragma unroll
    for (int q = 0; q < 4; ++q){
      int r = rowBase + wr * 64 + i * 16 + l4 * 4 + q;
      if (r >= M) continue;
      #pragma unroll
      for (int j = 0; j < 4; ++j){
        int c = colBase + wc * 64 + j * 16 + l15;
        if (c >= KP) continue;
        size_t o = (size_t)r * KP + c;
        if (c >= NC){ Ch[o] = 0; Cl[o] = 0; continue; }
        float v = acc[i][j][q];
        if (MODE) v += bias[c];
        if (MODE == 1) v = v > 0.f ? v : 0.01f * v;
        if (MODE == 2) v = v > 0.f ? v : (expf(v) - 1.f);
        pwrite(Ch, Cl, o, v);
      }
    }
  }
}

// ---------------- GRU v3: reg-A dbuf + LDS-W dbuf, pipelined ---------------
__global__ __launch_bounds__(256, 2) void k_gru(
    const us* __restrict__ Ih, const us* __restrict__ Il,
    const us* __restrict__ Hh, const us* __restrict__ Hl,
    const us* __restrict__ Wp,
    const float* __restrict__ bih, const float* __restrict__ bhh,
    us* __restrict__ Oh, us* __restrict__ Ol){
  __shared__ short lsW[2][12288];   // [t(12)][kg(4)][row(32)][8]
  const int tid = threadIdx.x, lane = tid & 63, wid = tid >> 6;
  const int l15 = lane & 15, l4 = lane >> 4;
  int work = xcd_chunk(blockIdx.x, gridDim.x);
  const int rt = work / 10, jt = work - rt * 10;
  const int rowBase = rt * 128;
  f32x4 acc[2][2][6] = {};
  const us* asrc[4] = {Ih, Il, Hh, Hl};
  bf16x8 fa[2][2][4];   // [buf][r][tensor]

  auto loadA = [&](int ks, int buf){
    int k0 = ks * 32;
    #pragma unroll
    for (int r = 0; r < 2; ++r){
      size_t base = (size_t)(rowBase + wid * 32 + r * 16 + l15) * KP + k0 + l4 * 8;
      #pragma unroll
      for (int t = 0; t < 4; ++t)
        fa[buf][r][t] = *(const bf16x8*)(asrc[t] + base);
    }
  };
  auto stageW = [&](int ks, int buf){
    const us* wsrc = Wp + (size_t)(jt * 10 + ks) * 12288;
    #pragma unroll
    for (int s = 0; s < 6; ++s){
      int lin = s * 256 + tid;
      __builtin_amdgcn_global_load_lds(
        (const __attribute__((address_space(1))) unsigned*)(wsrc + (size_t)lin * 8),
        (__attribute__((address_space(3))) unsigned*)(&lsW[buf][0] + (size_t)(s * 256 + (tid & ~63)) * 8),
        16, 0, 0);
    }
  };
  auto compute = [&](int buf){
    #pragma unroll
    for (int c = 0; c < 2; ++c){
      #pragma unroll
      for (int mg = 0; mg < 6; ++mg){
        const int m = mg / 3, g = mg % 3, tH = m * 6 + g * 2;
        int wro = c * 16 + l15;
        bf16x8 wh = *(const bf16x8*)(&lsW[buf][0] + (size_t)((tH * 4 + l4) * 32 + wro) * 8);
        bf16x8 wl = *(const bf16x8*)(&lsW[buf][0] + (size_t)(((tH + 1) * 4 + l4) * 32 + wro) * 8);
        #pragma unroll
        for (int r = 0; r < 2; ++r){
          acc[r][c][mg] = __builtin_amdgcn_mfma_f32_16x16x32_bf16(fa[buf][r][m*2],   wh, acc[r][c][mg], 0, 0, 0);
          acc[r][c][mg] = __builtin_amdgcn_mfma_f32_16x16x32_bf16(fa[buf][r][m*2],   wl, acc[r][c][mg], 0, 0, 0);
          acc[r][c][mg] = __builtin_amdgcn_mfma_f32_16x16x32_bf16(fa[buf][r][m*2+1], wh, acc[r][c][mg], 0, 0, 0);
        }
      }
    }
  };

  loadA(0, 0); stageW(0, 0);
  __syncthreads();
  for (int ks2 = 0; ks2 < 5; ++ks2){
    int ks = ks2 * 2;
    if (ks < 9){ loadA(ks + 1, 1); stageW(ks + 1, 1); }
    compute(0);
    __syncthreads();
    if (ks + 2 <= 9){ loadA(ks + 2, 0); stageW(ks + 2, 0); }
    compute(1);
    __syncthreads();
  }

  #pragma unroll
  for (int c = 0; c < 2; ++c){
    int j = jt * 32 + c * 16 + l15;
    bool jok = j < D;
    float b0=0.f,b1=0.f,b2=0.f,c0=0.f,c1=0.f,c2=0.f;
    if (jok){ b0=bih[j]; b1=bih[j+300]; b2=bih[j+600]; c0=bhh[j]; c1=bhh[j+300]; c2=bhh[j+600]; }
    #pragma unroll
    for (int r = 0; r < 2; ++r){
      #pragma unroll
      for (int q = 0; q < 4; ++q){
        int row = rowBase + wid * 32 + r * 16 + l4 * 4 + q;
        float o = 0.f;
        if (jok){
          float ir = acc[r][c][0][q] + b0, iz = acc[r][c][1][q] + b1, in_ = acc[r][c][2][q] + b2;
          float hr = acc[r][c][3][q] + c0, hz = acc[r][c][4][q] + c1, hn  = acc[r][c][5][q] + c2;
          float rg = 1.f / (1.f + expf(-(ir + hr)));
          float zg = 1.f / (1.f + expf(-(iz + hz)));
          float nn = tanhf(in_ + rg * hn);
          float h = pread(Hh, Hl, (size_t)row * KP + j);
          o = (1.f - zg) * nn + zg * h;
          o = o > 0.f ? o : 0.f;
        }
        if (j < KP) pwrite(Oh, Ol, (size_t)row * KP + j, o);
      }
    }
  }
}

// ---------------- init: planes of emb_atom[x0]+emb_chir[x1] ----------------
__global__ void k_embed2(const int* __restrict__ x, const float* __restrict__ ea,
                         const float* __restrict__ ec, us* __restrict__ hb,
                         us* __restrict__ lb, int N, int total){
  int idx = blockIdx.x * blockDim.x + threadIdx.x;
  if (idx >= total) return;
  int r = idx / KP, j = idx - r * KP;
  float v = (r < N && j < D) ? ea[x[2*r] * D + j] + ec[x[2*r+1] * D + j] : 0.f;
  pwrite(hb, lb, idx, v);
}

// ------- T[c][0..319] = (ge_e1[t]+ge_e2[d]) @ W1b^T, zero-padded ----------
__global__ void k_table(const float* __restrict__ e1, const float* __restrict__ e2,
                        const float* __restrict__ W1, float* __restrict__ T){
  int c = blockIdx.x, t = c / 3, d = c - 3 * (c / 3);
  __shared__ float se[D];
  for (int k = threadIdx.x; k < D; k += blockDim.x) se[k] = e1[t*D + k] + e2[d*D + k];
  __syncthreads();
  for (int j = threadIdx.x; j < KP; j += blockDim.x){
    float s = 0.f;
    if (j < D) for (int k = 0; k < D; ++k) s += se[k] * W1[(size_t)j * 600 + 300 + k];
    T[c * KP + j] = s;
  }
}

// ------- padded fp32 vector table vp[18][320] ------------------------------
__global__ void k_pads(const float* __restrict__ ge_att_l, const float* __restrict__ ge_att_r,
                       const float* __restrict__ gat_att_s, const float* __restrict__ gat_att_d,
                       const float* __restrict__ mol_att_s, const float* __restrict__ mol_att_d,
                       const float* __restrict__ gat_b, const float* __restrict__ mol_b,
                       const float* __restrict__ lin2_W, float* __restrict__ vp){
  int idx = blockIdx.x * blockDim.x + threadIdx.x;
  if (idx >= 18 * KP) return;
  int s = idx / KP, j = idx - s * KP;
  float v = 0.f;
  if (j < D){
    if (s == 0) v = ge_att_l[j];
    else if (s == 1) v = ge_att_r[j];
    else if (s < 6)  v = gat_att_s[(s - 2) * D + j];
    else if (s < 10) v = gat_att_d[(s - 6) * D + j];
    else if (s == 10) v = mol_att_s[j];
    else if (s == 11) v = mol_att_d[j];
    else if (s < 16) v = gat_b[(s - 12) * D + j];
    else if (s == 16) v = mol_b[j];
    else v = lin2_W[j];
  }
  vp[idx] = v;
}

__device__ __forceinline__ void load8f(const float* __restrict__ p, float* v){
  float4 a = *(const float4*)p, b = *(const float4*)(p + 4);
  v[0]=a.x; v[1]=a.y; v[2]=a.z; v[3]=a.w; v[4]=b.x; v[5]=b.y; v[6]=b.z; v[7]=b.w;
}
__device__ __forceinline__ void store8p(us* __restrict__ h, us* __restrict__ l,
                                        size_t ob, const float* v){
  ushort4 h0, h1, l0, l1;
  #pragma unroll
  for (int u = 0; u < 8; ++u){
    us hi = f2bf(v[u]), lo = f2bf(v[u] - bf2f(hi));
    if (u < 4){ ((us*)&h0)[u] = hi; ((us*)&l0)[u] = lo; }
    else      { ((us*)&h1)[u-4] = hi; ((us*)&l1)[u-4] = lo; }
  }
  *(ushort4*)(h + ob) = h0; *(ushort4*)(h + ob + 4) = h1;
  *(ushort4*)(l + ob) = l0; *(ushort4*)(l + ob + 4) = l1;
}

// ---------------- row dot (plane pair, padded vector) ---------------------
__global__ void k_dot2(const us* __restrict__ Ahp, const us* __restrict__ Alp,
                       const float* __restrict__ vp, float* __restrict__ out, int M){
  int w = (blockIdx.x * blockDim.x + threadIdx.x) >> 6;
  int lane = threadIdx.x & 63;
  if (w >= M) return;
  float s = 0.f;
  if (lane < 40){
    int jb = lane * 8;
    size_t b = (size_t)w * KP + jb;
    bf16x8 hv = *(const bf16x8*)(Ahp + b), lv = *(const bf16x8*)(Alp + b);
    float vv[8]; load8f(vp + jb, vv);
    #pragma unroll
    for (int u = 0; u < 8; ++u) s += (bf2f((us)hv[u]) + bf2f((us)lv[u])) * vv[u];
  }
  #pragma unroll
  for (int o = 32; o; o >>= 1) s += __shfl_xor(s, o);
  if (lane == 0) out[w] = s;
}

// ---------------- CSR build ------------------------------------------------
__global__ void k_hist(const int* __restrict__ ei, int E, int* __restrict__ hist){
  int e = blockIdx.x * blockDim.x + threadIdx.x;
  if (e < E) atomicAdd(&hist[ei[E + e]], 1);
}
template<int BS>
__global__ void k_scanA(const int* __restrict__ in, int* __restrict__ out,
                        int* __restrict__ bsum, int n){
  __shared__ int s[BS];
  int t = threadIdx.x, gid = blockIdx.x * BS + t;
  int v = (gid < n) ? in[gid] : 0;
  s[t] = v; __syncthreads();
  for (int o = 1; o < BS; o <<= 1){
    int add = (t >= o) ? s[t - o] : 0;
    __syncthreads();
    s[t] += add;
    __syncthreads();
  }
  if (gid < n) out[gid] = s[t] - v;
  if (t == BS - 1) bsum[blockIdx.x] = s[BS - 1];
}
template<int BS>
__global__ void k_scanB(int* __restrict__ bsum, int nb){
  __shared__ int s[BS];
  int t = threadIdx.x;
  int v = (t < nb) ? bsum[t] : 0;
  s[t] = v; __syncthreads();
  for (int o = 1; o < BS; o <<= 1){
    int add = (t >= o) ? s[t - o] : 0;
    __syncthreads();
    s[t] += add;
    __syncthreads();
  }
  if (t < nb) bsum[t] = s[t] - v;
}
template<int BS>
__global__ void k_scanC(int* __restrict__ out, const int* __restrict__ bsum, int n){
  int gid = blockIdx.x * BS + threadIdx.x;
  if (gid < n) out[gid] += bsum[blockIdx.x];
}
__global__ void k_setN(int* __restrict__ off, int N, int E){ off[N] = E; }
__global__ void k_fill(const int* __restrict__ ei, int E, const int* __restrict__ off,
                       int* __restrict__ cnt, int* __restrict__ lst){
  int e = blockIdx.x * blockDim.x + threadIdx.x;
  if (e >= E) return;
  int d = ei[E + e];
  int p = off[d] + atomicAdd(&cnt[d], 1);
  lst[p] = e;
}
__global__ void k_goff(const int* __restrict__ batch, int N, int G, int* __restrict__ goff){
  int g = blockIdx.x * blockDim.x + threadIdx.x;
  if (g > G) return;
  int lo = 0, hi = N;
  while (lo < hi){ int mid = (lo + hi) >> 1; if (batch[mid] < g) lo = mid + 1; else hi = mid; }
  goff[g] = lo;
}

// ---------------- fused GATEConv attention (online softmax, CSR) ----------
__global__ void k_gate_fused(const us* __restrict__ uh, const us* __restrict__ ul,
                             const float* __restrict__ Tp, const float* __restrict__ att_lp,
                             const float* __restrict__ rvec,
                             const int* __restrict__ ei, const int* __restrict__ ea,
                             const int* __restrict__ off, const int* __restrict__ lst,
                             us* __restrict__ oh, us* __restrict__ ol, int N){
  int d = (blockIdx.x * blockDim.x + threadIdx.x) >> 6;
  int lane = threadIdx.x & 63;
  if (d >= N) return;
  bool act = lane < 40;
  int jb = lane * 8;
  float al[8] = {};
  if (act) load8f(att_lp + jb, al);
  int beg = off[d], deg = off[d + 1] - beg;
  float rd = rvec[d];
  float accv[8] = {}, m = -1e30f, s = 0.f;
  for (int ii = 0; ii <= deg; ++ii){
    int src, c;
    if (ii < deg){ int e = lst[beg + ii]; src = ei[e]; c = ea[2*e] * 3 + ea[2*e + 1]; }
    else { src = d; c = 12; }
    float xv[8] = {}; float part = 0.f;
    if (act){
      size_t ub = (size_t)src * KP + jb;
      bf16x8 hv = *(const bf16x8*)(uh + ub), lv = *(const bf16x8*)(ul + ub);
      float tv[8]; load8f(Tp + c * KP + jb, tv);
      #pragma unroll
      for (int u = 0; u < 8; ++u){
        float v = bf2f((us)hv[u]) + bf2f((us)lv[u]) + tv[u];
        v = v > 0.f ? v : 0.01f * v;
        part += v * al[u];
        xv[u] = v;
      }
    }
    #pragma unroll
    for (int o = 32; o; o >>= 1) part += __shfl_xor(part, o);
    float l = part + rd; l = l > 0.f ? l : 0.01f * l;
    float mn = fmaxf(m, l);
    float sc = expf(m - mn), p = expf(l - mn);
    #pragma unroll
    for (int u = 0; u < 8; ++u) accv[u] = accv[u] * sc + p * xv[u];
    s = s * sc + p; m = mn;
  }
  if (act){
    float inv = 1.f / (s + 1e-16f);
    float v[8];
    #pragma unroll
    for (int u = 0; u < 8; ++u) v[u] = accv[u] * inv;
    store8p(oh, ol, (size_t)d * KP + jb, v);
  }
}

// ---------------- fused GATConv attention (+bias+elu) ---------------------
__global__ void k_gat_fused(const us* __restrict__ xh, const us* __restrict__ xl,
                            const float* __restrict__ as_, const float* __restrict__ ad,
                            const int* __restrict__ ei,
                            const int* __restrict__ off, const int* __restrict__ lst,
                            const float* __restrict__ biasp,
                            us* __restrict__ oh, us* __restrict__ ol, int N){
  int d = (blockIdx.x * blockDim.x + threadIdx.x) >> 6;
  int lane = threadIdx.x & 63;
  if (d >= N) return;
  bool act = lane < 40;
  int jb = lane * 8;
  int beg = off[d], deg = off[d + 1] - beg;
  float add = ad[d];
  float accv[8] = {}, m = -1e30f, s = 0.f;
  for (int ii = 0; ii < deg; ++ii){
    int e = lst[beg + ii];
    int src = ei[e];
    float l = as_[src] + add; l = l > 0.f ? l : 0.2f * l;
    float mn = fmaxf(m, l);
    float sc = expf(m - mn), p = expf(l - mn);
    if (act){
      size_t ub = (size_t)src * KP + jb;
      bf16x8 hv = *(const bf16x8*)(xh + ub), lv = *(const bf16x8*)(xl + ub);
      #pragma unroll
      for (int u = 0; u < 8; ++u)
        accv[u] = accv[u] * sc + p * (bf2f((us)hv[u]) + bf2f((us)lv[u]));
    }
    s = s * sc + p; m = mn;
  }
  if (act){
    float inv = 1.f / (s + 1e-16f);
    float bv[8]; load8f(biasp + jb, bv);
    float v[8];
    #pragma unroll
    for (int u = 0; u < 8; ++u){
      float w = accv[u] * inv + bv[u];
      v[u] = w > 0.f ? w : (expf(w) - 1.f);
    }
    store8p(oh, ol, (size_t)d * KP + jb, v);
  }
}

// ---------------- fused mol attention (+mol_b+elu) ------------------------
__global__ void k_mol_fused(const us* __restrict__ xh, const us* __restrict__ xl,
                            const float* __restrict__ asx, const float* __restrict__ adg,
                            const int* __restrict__ goff, const float* __restrict__ biasp,
                            us* __restrict__ oh, us* __restrict__ ol, int G){
  int g = (blockIdx.x * blockDim.x + threadIdx.x) >> 6;
  int lane = threadIdx.x & 63;
  if (g >= G) return;
  bool act = lane < 40;
  int jb = lane * 8;
  int beg = goff[g], end = goff[g + 1];
  float add = adg[g];
  float accv[8] = {}, m = -1e30f, s = 0.f;
  for (int i = beg; i < end; ++i){
    float l = asx[i] + add; l = l > 0.f ? l : 0.2f * l;
    float mn = fmaxf(m, l);
    float sc = expf(m - mn), p = expf(l - mn);
    if (act){
      size_t ub = (size_t)i * KP + jb;
      bf16x8 hv = *(const bf16x8*)(xh + ub), lv = *(const bf16x8*)(xl + ub);
      #pragma unroll
      for (int u = 0; u < 8; ++u)
        accv[u] = accv[u] * sc + p * (bf2f((us)hv[u]) + bf2f((us)lv[u]));
    }
    s = s * sc + p; m = mn;
  }
  if (act){
    float inv = 1.f / (s + 1e-16f);
    float bv[8]; load8f(biasp + jb, bv);
    float v[8];
    #pragma unroll
    for (int u = 0; u < 8; ++u){
      float w = accv[u] * inv + bv[u];
      v[u] = w > 0.f ? w : (expf(w) - 1.f);
    }
    store8p(oh, ol, (size_t)g * KP + jb, v);
  }
}

// ---------------- segment-sum + relu -> G planes --------------------------
__global__ void k_gsum(const us* __restrict__ xh, const us* __restrict__ xl,
                       const int* __restrict__ goff,
                       us* __restrict__ oh, us* __restrict__ ol, int G){
  int g = (blockIdx.x * blockDim.x + threadIdx.x) >> 6;
  int lane = threadIdx.x & 63;
  if (g >= G) return;
  bool act = lane < 40;
  int jb = lane * 8;
  int beg = goff[g], end = goff[g + 1];
  float a[8] = {};
  if (act){
    for (int i = beg; i < end; ++i){
      size_t ub = (size_t)i * KP + jb;
      bf16x8 hv = *(const bf16x8*)(xh + ub), lv = *(const bf16x8*)(xl + ub);
      #pragma unroll
      for (int u = 0; u < 8; ++u) a[u] += bf2f((us)hv[u]) + bf2f((us)lv[u]);
    }
    float v[8];
    #pragma unroll
    for (int u = 0; u < 8; ++u) v[u] = fmaxf(a[u], 0.f);
    store8p(oh, ol, (size_t)g * KP + jb, v);
  }
}

// ---------------- final: out fp32 + pred ----------------------------------
__global__ void k_final2(const us* __restrict__ Oh, const us* __restrict__ Ol,
                         const float* __restrict__ w2p, const float* __restrict__ b2,
                         float* __restrict__ out, int G){
  int g = (blockIdx.x * blockDim.x + threadIdx.x) >> 6;
  int lane = threadIdx.x & 63;
  if (g >= G) return;
  float s = 0.f;
  if (lane < 40){
    int jb = lane * 8;
    size_t b = (size_t)g * KP + jb;
    bf16x8 hv = *(const bf16x8*)(Oh + b), lv = *(const bf16x8*)(Ol + b);
    float wv[8]; load8f(w2p + jb, wv);
    #pragma unroll
    for (int u = 0; u < 8; ++u){
      float v = bf2f((us)hv[u]) + bf2f((us)lv[u]);
      if (jb + u < D) out[(size_t)g * D + jb + u] = v;
      s += v * wv[u];
    }
  }
  #pragma unroll
  for (int o = 32; o; o >>= 1) s += __shfl_xor(s, o);
  if (lane == 0) out[(size_t)G * D + g] = s + b2[0];
}

// ===========================================================================
extern "C" void kernel_launch(void* const* d_in, const int* in_sizes, int n_in,
                              void* d_out, int out_size, void* d_ws, size_t ws_size,
                              hipStream_t stream){
  (void)n_in; (void)ws_size;
  const int*   x         = (const int*)d_in[0];
  const int*   ei        = (const int*)d_in[1];
  const int*   ea        = (const int*)d_in[2];
  const int*   batch     = (const int*)d_in[3];
  const float* emb_atom  = (const float*)d_in[4];
  const float* emb_chir  = (const float*)d_in[5];
  const float* lin1_W    = (const float*)d_in[6];
  const float* lin1_b    = (const float*)d_in[7];
  const float* ge_e1     = (const float*)d_in[8];
  const float* ge_e2     = (const float*)d_in[9];
  const float* ge_att_l  = (const float*)d_in[10];
  const float* ge_att_r  = (const float*)d_in[11];
  const float* ge_lin1_W = (const float*)d_in[12];
  const float* ge_lin2_W = (const float*)d_in[13];
  const float* ge_bias   = (const float*)d_in[14];
  const float* gat_W     = (const float*)d_in[15];
  const float* gat_att_s = (const float*)d_in[16];
  const float* gat_att_d = (const float*)d_in[17];
  const float* gat_b     = (const float*)d_in[18];
  const float* gru_wih   = (const float*)d_in[19];
  const float* gru_whh   = (const float*)d_in[20];
  const float* gru_bih   = (const float*)d_in[21];
  const float* gru_bhh   = (const float*)d_in[22];
  const float* mol_Ws    = (const float*)d_in[23];
  const float* mol_Wd    = (const float*)d_in[24];
  const float* mol_att_s = (const float*)d_in[25];
  const float* mol_att_d = (const float*)d_in[26];
  const float* mol_b     = (const float*)d_in[27];
  const float* mgru_wih  = (const float*)d_in[28];
  const float* mgru_whh  = (const float*)d_in[29];
  const float* mgru_bih  = (const float*)d_in[30];
  const float* mgru_bhh  = (const float*)d_in[31];
  const float* lin2_W    = (const float*)d_in[32];
  const float* lin2_b    = (const float*)d_in[33];

  const int N  = in_sizes[0] / 2;
  const int E  = in_sizes[1] / 2;
  const int G  = out_size / (D + 1);
  const int Npad = cdiv(N, 128) * 128;
  const int Gpad = cdiv(G, 128) * 128;

  char* base = (char*)d_ws;
  size_t used = 0;
  auto alloc = [&](size_t bytes) -> void* {
    void* p = base + used;
    used += (bytes + 255) & ~(size_t)255;
    return p;
  };
  // three N-row plane pairs
  us* PaH = (us*)alloc((size_t)Npad * KP * 2); us* PaL = (us*)alloc((size_t)Npad * KP * 2);
  us* PbH = (us*)alloc((size_t)Npad * KP * 2); us* PbL = (us*)alloc((size_t)Npad * KP * 2);
  us* PcH = (us*)alloc((size_t)Npad * KP * 2); us* PcL = (us*)alloc((size_t)Npad * KP * 2);
  // three G-row plane pairs
  us* QaH = (us*)alloc((size_t)Gpad * KP * 2); us* QaL = (us*)alloc((size_t)Gpad * KP * 2);
  us* QbH = (us*)alloc((size_t)Gpad * KP * 2); us* QbL = (us*)alloc((size_t)Gpad * KP * 2);
  us* QcH = (us*)alloc((size_t)Gpad * KP * 2); us* QcL = (us*)alloc((size_t)Gpad * KP * 2);
  // small weights (plane pairs, 384 rows)
  auto wsm = [&](void){ return (us*)alloc((size_t)384 * KP * 2); };
  us *wlin1H=wsm(), *wlin1L=wsm(), *wgeuH=wsm(), *wgeuL=wsm(), *wge2H=wsm(), *wge2L=wsm();
  us *wgatH[4], *wgatL[4];
  for (int l = 0; l < 4; ++l){ wgatH[l]=wsm(); wgatL[l]=wsm(); }
  us *wmolSH=wsm(), *wmolSL=wsm(), *wmolDH=wsm(), *wmolDL=wsm();
  // packed GRU weights: 6 sets
  us* Wgru[6];
  for (int l = 0; l < 6; ++l) Wgru[l] = (us*)alloc((size_t)1228800 * 2);
  float* Tt  = (float*)alloc((size_t)18 * KP * 4);
  float* vp  = (float*)alloc((size_t)18 * KP * 4);
  float* rv  = (float*)alloc((size_t)N * 4);
  float* adv = (float*)alloc((size_t)N * 4);
  float* asx = (float*)alloc((size_t)N * 4);
  // CSR
  const int SBS = 512;
  int nblk = cdiv(N, SBS);
  int* hist = (int*)alloc((size_t)N * 4);
  int* cnt  = (int*)alloc((size_t)N * 4);
  int* off  = (int*)alloc((size_t)(N + 1) * 4);
  int* bsum = (int*)alloc((size_t)nblk * 4);
  int* lst  = (int*)alloc((size_t)E * 4);
  int* goff = (int*)alloc((size_t)(G + 1) * 4);

  auto cvt2 = [&](const float* src, int ld, int M, us* hb, us* lb, int Mpad){
    int tot = Mpad * 80;
    k_cvt2<<<cdiv(tot, 256), 256, 0, stream>>>(src, ld, M, hb, lb, tot);
  };
  auto mm_p = [&](const us* ah, const us* al, const us* bh, const us* bl,
                  const float* bias, us* ch, us* cl, int M, int NC, int mode){
    int nwg = cdiv(M, 128) * 3;
    if (mode == 0)      k_mfma3<0><<<nwg, 256, 0, stream>>>(ah, al, bh, bl, bias, ch, cl, M, NC);
    else if (mode == 1) k_mfma3<1><<<nwg, 256, 0, stream>>>(ah, al, bh, bl, bias, ch, cl, M, NC);
    else                k_mfma3<2><<<nwg, 256, 0, stream>>>(ah, al, bh, bl, bias, ch, cl, M, NC);
  };
  auto gru = [&](const us* Ih, const us* Il, const us* Hh, const us* Hl,
                 const us* Wp, const float* bi, const float* bh,
                 us* Oh, us* Ol, int Mpad){
    int nwg = (Mpad / 128) * 10;
    k_gru<<<nwg, 256, 0, stream>>>(Ih, Il, Hh, Hl, Wp, bi, bh, Oh, Ol);
  };

  // ---- CSR build ----
  hipMemsetAsync(hist, 0, (size_t)N * 4, stream);
  k_hist<<<cdiv(E, 256), 256, 0, stream>>>(ei, E, hist);
  k_scanA<SBS><<<nblk, SBS, 0, stream>>>(hist, off, bsum, N);
  k_scanB<SBS><<<1, SBS, 0, stream>>>(bsum, nblk);
  k_scanC<SBS><<<nblk, SBS, 0, stream>>>(off, bsum, N);
  k_setN<<<1, 1, 0, stream>>>(off, N, E);
  hipMemsetAsync(cnt, 0, (size_t)N * 4, stream);
  k_fill<<<cdiv(E, 256), 256, 0, stream>>>(ei, E, off, cnt, lst);
  k_goff<<<cdiv(G + 1, 256), 256, 0, stream>>>(batch, N, G, goff);

  // ---- weights -> planes / packs / padded vectors ----
  cvt2(lin1_W, D, D, wlin1H, wlin1L, 384);
  cvt2(ge_lin1_W, 2 * D, D, wgeuH, wgeuL, 384);
  cvt2(ge_lin2_W, D, D, wge2H, wge2L, 384);
  for (int l = 0; l < 4; ++l) cvt2(gat_W + (size_t)l * D * D, D, D, wgatH[l], wgatL[l], 384);
  cvt2(mol_Ws, D, D, wmolSH, wmolSL, 384);
  cvt2(mol_Wd, D, D, wmolDH, wmolDL, 384);
  for (int l = 0; l < 5; ++l)
    k_wpack<<<1200, 256, 0, stream>>>(gru_wih + (size_t)l * 270000,
                                      gru_whh + (size_t)l * 270000, Wgru[l]);
  k_wpack<<<1200, 256, 0, stream>>>(mgru_wih, mgru_whh, Wgru[5]);
  k_table<<<18, 256, 0, stream>>>(ge_e1, ge_e2, ge_lin1_W, Tt);
  k_pads<<<cdiv(18 * KP, 256), 256, 0, stream>>>(ge_att_l, ge_att_r, gat_att_s, gat_att_d,
                                                 mol_att_s, mol_att_d, gat_b, mol_b, lin2_W, vp);

  // ---- init features ----
  k_embed2<<<cdiv(Npad * KP, 256), 256, 0, stream>>>(x, emb_atom, emb_chir, PaH, PaL, N, Npad * KP);
  mm_p(PaH, PaL, wlin1H, wlin1L, lin1_b, PbH, PbL, N, D, 1);       // xf -> Pb

  // ---- GATEConv ----
  mm_p(PbH, PbL, wgeuH, wgeuL, nullptr, PaH, PaL, N, D, 0);        // u -> Pa
  k_dot2<<<cdiv(N, 4), 256, 0, stream>>>(PbH, PbL, vp + 1 * KP, rv, N);
  k_gate_fused<<<cdiv(N, 4), 256, 0, stream>>>(PaH, PaL, Tt, vp, rv,
                                               ei, ea, off, lst, PcH, PcL, N);
  mm_p(PcH, PcL, wge2H, wge2L, ge_bias, PaH, PaL, N, D, 2);        // elu(h) -> Pa
  gru(PaH, PaL, PbH, PbL, Wgru[0], gru_bih, gru_bhh, PcH, PcL, Npad);   // xf -> Pc

  us *xfH = PcH, *xfL = PcL, *aH = PaH, *aL = PaL, *bH = PbH, *bL = PbL;
  // ---- GATConv layers 1..4 ----
  for (int l = 0; l < 4; ++l){
    mm_p(xfH, xfL, wgatH[l], wgatL[l], nullptr, aH, aL, N, D, 0);  // xw -> a
    k_dot2<<<cdiv(N, 4), 256, 0, stream>>>(aH, aL, vp + (2 + l) * KP, rv, N);
    k_dot2<<<cdiv(N, 4), 256, 0, stream>>>(aH, aL, vp + (6 + l) * KP, adv, N);
    k_gat_fused<<<cdiv(N, 4), 256, 0, stream>>>(aH, aL, rv, adv, ei, off, lst,
                                                vp + (12 + l) * KP, bH, bL, N);
    gru(bH, bL, xfH, xfL, Wgru[l + 1],
        gru_bih + (l + 1) * 900, gru_bhh + (l + 1) * 900, aH, aL, Npad);  // xf' -> a
    us* th = xfH; us* tl = xfL;
    xfH = aH; xfL = aL; aH = th; aL = tl;
  }

  // ---- attentive readout ----
  k_gsum<<<cdiv(G, 4), 256, 0, stream>>>(xfH, xfL, goff, QaH, QaL, G);      // OUT -> Qa
  mm_p(xfH, xfL, wmolSH, wmolSL, nullptr, aH, aL, N, D, 0);                 // xs -> a (pinned)
  k_dot2<<<cdiv(N, 4), 256, 0, stream>>>(aH, aL, vp + 10 * KP, asx, N);
  us *outH = QaH, *outL = QaL, *sgH = QbH, *sgL = QbL, *xdH = QcH, *xdL = QcL;
  for (int t = 0; t < 3; ++t){
    mm_p(outH, outL, wmolDH, wmolDL, nullptr, xdH, xdL, G, D, 0);           // xd
    k_dot2<<<cdiv(G, 4), 256, 0, stream>>>(xdH, xdL, vp + 11 * KP, adv, G);
    k_mol_fused<<<cdiv(G, 4), 256, 0, stream>>>(aH, aL, asx, adv, goff,
                                                vp + 16 * KP, sgH, sgL, G);
    gru(sgH, sgL, outH, outL, Wgru[5], mgru_bih, mgru_bhh, xdH, xdL, Gpad); // out' -> xd
    us* th = outH; us* tl = outL;
    outH = xdH; outL = xdL; xdH = th; xdL = tl;
  }
  k_final2<<<cdiv(G, 4), 256, 0, stream>>>(outH, outL, vp + 17 * KP, lin2_b, (float*)d_out, G);
}